// Round 1
// baseline (1009.469 us; speedup 1.0000x reference)
//
#include <hip/hip_runtime.h>
#include <math.h>

// ---------------------------------------------------------------------------
// GraphTransformerBlock: TransformerConv (4 heads x 32) + residual MLP
// fp32 throughout. Softmax computed WITHOUT max subtraction (shift-invariant,
// no overflow risk since |alpha| < ~10), enabling a single fused edge pass.
// ---------------------------------------------------------------------------

#define D 128           // HID == D_IN
#define EDIM 32
#define NHEAD 4
#define TILE_M 64
#define KCH 32
#define EPB 32          // edges per block in edge kernel

__device__ inline float gelu_tanh(float x) {
    float x3 = x * x * x;
    float u = 0.7978845608028654f * (x + 0.044715f * x3);
    return 0.5f * x * (1.0f + tanhf(u));
}

// ---------------------------------------------------------------------------
// Kernel 1: q/k/v/skip = x @ W + b.  grid (ceil(N/64), 4), block 256.
// 64 rows x 128 cols per block, K=128 in chunks of 32.
// ---------------------------------------------------------------------------
__global__ __launch_bounds__(256) void gemm_qkvs(
    const float* __restrict__ x,
    const float* __restrict__ Wq, const float* __restrict__ bq,
    const float* __restrict__ Wk, const float* __restrict__ bk,
    const float* __restrict__ Wv, const float* __restrict__ bv,
    const float* __restrict__ Ws, const float* __restrict__ bs,
    float* __restrict__ Q, float* __restrict__ K,
    float* __restrict__ V, float* __restrict__ S, int N)
{
    const int m = blockIdx.y;
    const float* W = (m == 0) ? Wq : (m == 1) ? Wk : (m == 2) ? Wv : Ws;
    const float* b = (m == 0) ? bq : (m == 1) ? bk : (m == 2) ? bv : bs;
    float* O       = (m == 0) ? Q  : (m == 1) ? K  : (m == 2) ? V  : S;

    const int row0 = blockIdx.x * TILE_M;
    __shared__ float sA[TILE_M * KCH];   // [row][k]
    __shared__ float sB[KCH * D];        // [k][col]

    const int t = threadIdx.x;
    const int c = t & 127;
    const int rbase = (t >> 7) * 32;

    float acc[32];
#pragma unroll
    for (int r = 0; r < 32; ++r) acc[r] = 0.f;

    for (int kk = 0; kk < D; kk += KCH) {
#pragma unroll
        for (int i = 0; i < 8; ++i) {             // 64*32 elems / 256 thr
            int idx = t + i * 256;
            int r = idx >> 5, k = idx & 31;
            int gr = row0 + r;
            sA[idx] = (gr < N) ? x[gr * D + kk + k] : 0.f;
        }
#pragma unroll
        for (int i = 0; i < 16; ++i) {            // 32*128 elems / 256 thr
            int idx = t + i * 256;
            sB[idx] = W[(kk + (idx >> 7)) * D + (idx & 127)];
        }
        __syncthreads();
#pragma unroll
        for (int k4 = 0; k4 < 8; ++k4) {
            float w0 = sB[(k4 * 4 + 0) * D + c];
            float w1 = sB[(k4 * 4 + 1) * D + c];
            float w2 = sB[(k4 * 4 + 2) * D + c];
            float w3 = sB[(k4 * 4 + 3) * D + c];
#pragma unroll
            for (int r = 0; r < 32; ++r) {
                const float4 a = *reinterpret_cast<const float4*>(
                    &sA[(rbase + r) * KCH + k4 * 4]);
                acc[r] = fmaf(a.x, w0, fmaf(a.y, w1, fmaf(a.z, w2, fmaf(a.w, w3, acc[r]))));
            }
        }
        __syncthreads();
    }

    const float bias = b[c];
#pragma unroll
    for (int r = 0; r < 32; ++r) {
        int gr = row0 + rbase + r;
        if (gr < N) O[gr * D + c] = acc[r] + bias;
    }
}

// ---------------------------------------------------------------------------
// Kernel 2: fused edge pass. block 256 = 2 edge-slots x 128 lanes.
// Per edge: e = edge_attr@We (We column in regs, edge_attr via readlane),
// alpha = dot(q[dst], k[src]+e)/sqrt(32) per head (shfl_xor reduce over 32),
// ex = exp(alpha); atomicAdd denom[dst,h]; atomicAdd agg[dst,:] += (v[src]+e)*ex
// ---------------------------------------------------------------------------
__global__ __launch_bounds__(256) void edge_pass(
    const int* __restrict__ EI, const float* __restrict__ EA,
    const float* __restrict__ We,
    const float* __restrict__ Q, const float* __restrict__ K,
    const float* __restrict__ V,
    float* __restrict__ AGG, float* __restrict__ DEN, int E)
{
    const int t = threadIdx.x;
    const int d = t & 127;       // output dim
    const int slot = t >> 7;     // 0/1: which edge this half-block handles
    const int h = d >> 5;        // head

    // We column d -> registers (reused across all EPB edges of this block)
    float wcol[EDIM];
#pragma unroll
    for (int k = 0; k < EDIM; ++k) wcol[k] = We[k * D + d];

    const int ebase = blockIdx.x * EPB;

    for (int it = 0; it < EPB / 2; ++it) {
        const int eid = ebase + it * 2 + slot;
        if (eid >= E) continue;

        const int src = EI[eid];
        const int dst = EI[E + eid];

        // every wave: lanes 0..31 hold edge_attr[eid][0..31]
        const float eav = EA[eid * EDIM + (d & 31)];

        float e_d = 0.f;
#pragma unroll
        for (int k = 0; k < EDIM; ++k)
            e_d = fmaf(__shfl(eav, k, 64), wcol[k], e_d);

        const float kj = K[src * D + d] + e_d;
        float p = Q[dst * D + d] * kj;
        // reduce over the 32 lanes of this head (offsets <32 stay in-half)
#pragma unroll
        for (int off = 16; off; off >>= 1) p += __shfl_xor(p, off, 64);

        const float ex = expf(p * 0.17677669529663689f);   // 1/sqrt(32)

        if ((d & 31) == 0) atomicAdd(&DEN[dst * NHEAD + h], ex);

        const float vj = V[src * D + d] + e_d;
        atomicAdd(&AGG[dst * D + d], vj * ex);
    }
}

// ---------------------------------------------------------------------------
// Kernel 3: combine (agg/denom + skip) fused into MLP layer-1 A-load.
// Writes combined "out" back into OUT (was skip), h1 = gelu(out@W1+b1).
// ---------------------------------------------------------------------------
__global__ __launch_bounds__(256) void mlp1_kernel(
    const float* __restrict__ AGG, const float* __restrict__ DEN,
    float* __restrict__ OUT,
    const float* __restrict__ W1, const float* __restrict__ b1,
    float* __restrict__ H1, int N)
{
    const int row0 = blockIdx.x * TILE_M;
    __shared__ float sA[TILE_M * KCH];
    __shared__ float sB[KCH * D];

    const int t = threadIdx.x;
    const int c = t & 127;
    const int rbase = (t >> 7) * 32;

    float acc[32];
#pragma unroll
    for (int r = 0; r < 32; ++r) acc[r] = 0.f;

    for (int kk = 0; kk < D; kk += KCH) {
#pragma unroll
        for (int i = 0; i < 8; ++i) {
            int idx = t + i * 256;
            int r = idx >> 5, k = idx & 31;
            int gr = row0 + r;
            float val = 0.f;
            if (gr < N) {
                int col = kk + k;
                float den = DEN[gr * NHEAD + (col >> 5)] + 1e-16f;
                val = AGG[gr * D + col] / den + OUT[gr * D + col];
                OUT[gr * D + col] = val;  // persist combined out for residual
            }
            sA[idx] = val;
        }
#pragma unroll
        for (int i = 0; i < 16; ++i) {
            int idx = t + i * 256;
            sB[idx] = W1[(kk + (idx >> 7)) * D + (idx & 127)];
        }
        __syncthreads();
#pragma unroll
        for (int k4 = 0; k4 < 8; ++k4) {
            float w0 = sB[(k4 * 4 + 0) * D + c];
            float w1 = sB[(k4 * 4 + 1) * D + c];
            float w2 = sB[(k4 * 4 + 2) * D + c];
            float w3 = sB[(k4 * 4 + 3) * D + c];
#pragma unroll
            for (int r = 0; r < 32; ++r) {
                const float4 a = *reinterpret_cast<const float4*>(
                    &sA[(rbase + r) * KCH + k4 * 4]);
                acc[r] = fmaf(a.x, w0, fmaf(a.y, w1, fmaf(a.z, w2, fmaf(a.w, w3, acc[r]))));
            }
        }
        __syncthreads();
    }

    const float bias = b1[c];
#pragma unroll
    for (int r = 0; r < 32; ++r) {
        int gr = row0 + rbase + r;
        if (gr < N) H1[gr * D + c] = gelu_tanh(acc[r] + bias);
    }
}

// ---------------------------------------------------------------------------
// Kernel 4: h2 = gelu(h1@W2+b2); final = out + h2 -> d_out
// ---------------------------------------------------------------------------
__global__ __launch_bounds__(256) void mlp2_kernel(
    const float* __restrict__ H1, const float* __restrict__ OUT,
    const float* __restrict__ W2, const float* __restrict__ b2,
    float* __restrict__ FINAL, int N)
{
    const int row0 = blockIdx.x * TILE_M;
    __shared__ float sA[TILE_M * KCH];
    __shared__ float sB[KCH * D];

    const int t = threadIdx.x;
    const int c = t & 127;
    const int rbase = (t >> 7) * 32;

    float acc[32];
#pragma unroll
    for (int r = 0; r < 32; ++r) acc[r] = 0.f;

    for (int kk = 0; kk < D; kk += KCH) {
#pragma unroll
        for (int i = 0; i < 8; ++i) {
            int idx = t + i * 256;
            int r = idx >> 5, k = idx & 31;
            int gr = row0 + r;
            sA[idx] = (gr < N) ? H1[gr * D + kk + k] : 0.f;
        }
#pragma unroll
        for (int i = 0; i < 16; ++i) {
            int idx = t + i * 256;
            sB[idx] = W2[(kk + (idx >> 7)) * D + (idx & 127)];
        }
        __syncthreads();
#pragma unroll
        for (int k4 = 0; k4 < 8; ++k4) {
            float w0 = sB[(k4 * 4 + 0) * D + c];
            float w1 = sB[(k4 * 4 + 1) * D + c];
            float w2 = sB[(k4 * 4 + 2) * D + c];
            float w3 = sB[(k4 * 4 + 3) * D + c];
#pragma unroll
            for (int r = 0; r < 32; ++r) {
                const float4 a = *reinterpret_cast<const float4*>(
                    &sA[(rbase + r) * KCH + k4 * 4]);
                acc[r] = fmaf(a.x, w0, fmaf(a.y, w1, fmaf(a.z, w2, fmaf(a.w, w3, acc[r]))));
            }
        }
        __syncthreads();
    }

    const float bias = b2[c];
#pragma unroll
    for (int r = 0; r < 32; ++r) {
        int gr = row0 + rbase + r;
        if (gr < N) FINAL[gr * D + c] = OUT[gr * D + c] + gelu_tanh(acc[r] + bias);
    }
}

// ---------------------------------------------------------------------------
extern "C" void kernel_launch(void* const* d_in, const int* in_sizes, int n_in,
                              void* d_out, int out_size, void* d_ws, size_t ws_size,
                              hipStream_t stream)
{
    const float* x   = (const float*)d_in[0];
    const int*   EI  = (const int*)  d_in[1];
    const float* EA  = (const float*)d_in[2];
    const float* Wq  = (const float*)d_in[3];
    const float* bq  = (const float*)d_in[4];
    const float* Wk  = (const float*)d_in[5];
    const float* bk  = (const float*)d_in[6];
    const float* Wv  = (const float*)d_in[7];
    const float* bv  = (const float*)d_in[8];
    const float* We  = (const float*)d_in[9];
    const float* Wsk = (const float*)d_in[10];
    const float* bsk = (const float*)d_in[11];
    const float* W1  = (const float*)d_in[12];
    const float* b1  = (const float*)d_in[13];
    const float* W2  = (const float*)d_in[14];
    const float* b2  = (const float*)d_in[15];

    const int N = in_sizes[0] / D;
    const int E = in_sizes[1] / 2;

    float* ws = (float*)d_ws;
    float* Qb   = ws;                 // N*D
    float* Kb   = Qb  + (size_t)N * D;
    float* Vb   = Kb  + (size_t)N * D;
    float* Sb   = Vb  + (size_t)N * D;   // skip, then combined "out"
    float* AGGb = Sb  + (size_t)N * D;
    float* DENb = AGGb + (size_t)N * D;  // N*4
    float* H1b  = Qb;                    // alias: Q dead after edge pass

    // zero accumulators (atomics accumulate; harness does not re-poison)
    hipMemsetAsync(AGGb, 0, (size_t)N * D * sizeof(float), stream);
    hipMemsetAsync(DENb, 0, (size_t)N * NHEAD * sizeof(float), stream);

    const int NB = (N + TILE_M - 1) / TILE_M;

    gemm_qkvs<<<dim3(NB, 4), 256, 0, stream>>>(
        x, Wq, bq, Wk, bk, Wv, bv, Wsk, bsk, Qb, Kb, Vb, Sb, N);

    const int EB = (E + EPB - 1) / EPB;
    edge_pass<<<EB, 256, 0, stream>>>(EI, EA, We, Qb, Kb, Vb, AGGb, DENb, E);

    mlp1_kernel<<<NB, 256, 0, stream>>>(AGGb, DENb, Sb, W1, b1, H1b, N);
    mlp2_kernel<<<NB, 256, 0, stream>>>(H1b, Sb, W2, b2, (float*)d_out, N);
}

// Round 2
// 971.096 us; speedup vs baseline: 1.0395x; 1.0395x over previous
//
#include <hip/hip_runtime.h>
#include <math.h>

// ---------------------------------------------------------------------------
// GraphTransformerBlock: TransformerConv (4 heads x 32) + residual MLP.
// Round 2: atomics eliminated via CSR-by-dst + gather; edge MLP factored:
//   q.e        = ea . QE[dst]        (QE = per-node 4x32, computed inline)
//   sum a_e*e  = We^T (sum a_e*ea_e) (applied once per node after the loop)
// Softmax without max-subtraction (shift-invariant, |alpha|<~10).
// ---------------------------------------------------------------------------

#define D 128
#define EDIM 32
#define NHEAD 4
#define TILE_M 64
#define KCH 32

__device__ inline float gelu_tanh(float x) {
    float x3 = x * x * x;
    float u = 0.7978845608028654f * (x + 0.044715f * x3);
    return 0.5f * x * (1.0f + tanhf(u));
}

// ---------------------------------------------------------------------------
// Kernel 1: q/k/v/skip = x @ W + b.  grid (ceil(N/64), 4), block 256.
// ---------------------------------------------------------------------------
__global__ __launch_bounds__(256) void gemm_qkvs(
    const float* __restrict__ x,
    const float* __restrict__ Wq, const float* __restrict__ bq,
    const float* __restrict__ Wk, const float* __restrict__ bk,
    const float* __restrict__ Wv, const float* __restrict__ bv,
    const float* __restrict__ Ws, const float* __restrict__ bs,
    float* __restrict__ Q, float* __restrict__ K,
    float* __restrict__ V, float* __restrict__ S, int N)
{
    const int m = blockIdx.y;
    const float* W = (m == 0) ? Wq : (m == 1) ? Wk : (m == 2) ? Wv : Ws;
    const float* b = (m == 0) ? bq : (m == 1) ? bk : (m == 2) ? bv : bs;
    float* O       = (m == 0) ? Q  : (m == 1) ? K  : (m == 2) ? V  : S;

    const int row0 = blockIdx.x * TILE_M;
    __shared__ float sA[TILE_M * KCH];
    __shared__ float sB[KCH * D];

    const int t = threadIdx.x;
    const int c = t & 127;
    const int rbase = (t >> 7) * 32;

    float acc[32];
#pragma unroll
    for (int r = 0; r < 32; ++r) acc[r] = 0.f;

    for (int kk = 0; kk < D; kk += KCH) {
#pragma unroll
        for (int i = 0; i < 8; ++i) {
            int idx = t + i * 256;
            int r = idx >> 5, k = idx & 31;
            int gr = row0 + r;
            sA[idx] = (gr < N) ? x[gr * D + kk + k] : 0.f;
        }
#pragma unroll
        for (int i = 0; i < 16; ++i) {
            int idx = t + i * 256;
            sB[idx] = W[(kk + (idx >> 7)) * D + (idx & 127)];
        }
        __syncthreads();
#pragma unroll
        for (int k4 = 0; k4 < 8; ++k4) {
            float w0 = sB[(k4 * 4 + 0) * D + c];
            float w1 = sB[(k4 * 4 + 1) * D + c];
            float w2 = sB[(k4 * 4 + 2) * D + c];
            float w3 = sB[(k4 * 4 + 3) * D + c];
#pragma unroll
            for (int r = 0; r < 32; ++r) {
                const float4 a = *reinterpret_cast<const float4*>(
                    &sA[(rbase + r) * KCH + k4 * 4]);
                acc[r] = fmaf(a.x, w0, fmaf(a.y, w1, fmaf(a.z, w2, fmaf(a.w, w3, acc[r]))));
            }
        }
        __syncthreads();
    }

    const float bias = b[c];
#pragma unroll
    for (int r = 0; r < 32; ++r) {
        int gr = row0 + rbase + r;
        if (gr < N) O[gr * D + c] = acc[r] + bias;
    }
}

// ---------------------------------------------------------------------------
// CSR construction
// ---------------------------------------------------------------------------
__global__ __launch_bounds__(256) void hist_kernel(
    const int* __restrict__ EI, int* __restrict__ deg, int E)
{
    int e = blockIdx.x * 256 + threadIdx.x;
    if (e < E) atomicAdd(&deg[EI[E + e]], 1);
}

// single-block chunked Hillis-Steele scan: rowptr[0]=0, rowptr[i+1]=incl[i]
__global__ __launch_bounds__(1024) void scan_kernel(
    const int* __restrict__ deg, int* __restrict__ rowptr, int N)
{
    __shared__ int tmp[1024];
    __shared__ int carry_s;
    const int t = threadIdx.x;
    if (t == 0) { carry_s = 0; rowptr[0] = 0; }
    __syncthreads();
    for (int base = 0; base < N; base += 1024) {
        int v = (base + t < N) ? deg[base + t] : 0;
        tmp[t] = v;
        __syncthreads();
        for (int off = 1; off < 1024; off <<= 1) {
            int add = (t >= off) ? tmp[t - off] : 0;
            __syncthreads();
            tmp[t] += add;
            __syncthreads();
        }
        if (base + t < N) rowptr[base + t + 1] = tmp[t] + carry_s;
        __syncthreads();
        if (t == 0) carry_s += tmp[1023];
        __syncthreads();
    }
}

__global__ __launch_bounds__(256) void scatter_kernel(
    const int* __restrict__ EI, int* __restrict__ cursor,
    int* __restrict__ eids, int* __restrict__ srcs, int E)
{
    int e = blockIdx.x * 256 + threadIdx.x;
    if (e < E) {
        int dst = EI[E + e];
        int pos = atomicAdd(&cursor[dst], 1);
        eids[pos] = e;
        srcs[pos] = EI[e];
    }
}

// ---------------------------------------------------------------------------
// Kernel: gather-aggregate. 128 threads per dst node (2 nodes / 256-block).
// Writes combined out (attention + skip) in place into S.
// ---------------------------------------------------------------------------
__global__ __launch_bounds__(256) void gather_pass(
    const int* __restrict__ rowptr, const int* __restrict__ eids,
    const int* __restrict__ srcs,
    const float* __restrict__ EA, const float* __restrict__ We,
    const float* __restrict__ Q, const float* __restrict__ K,
    const float* __restrict__ V, float* __restrict__ S, int N)
{
    const int t = threadIdx.x;
    const int d = t & 127;          // output dim 0..127
    const int slot = t >> 7;        // node slot within block
    const int n = blockIdx.x * 2 + slot;
    const int c = d & 31;           // channel within head (also k-index)
    const int hb = d & 96;          // h*32
    const int lsrc = d & 32;        // head-group base lane within the wave

    // We column d (for the per-node correction), reused across the node
    float wcol[32];
#pragma unroll
    for (int k = 0; k < 32; ++k) wcol[k] = We[k * D + d];

    if (n >= N) return;

    const float qd = Q[(size_t)n * D + d];

    // QE[h, k=c] = sum_cc q[h,cc] * We[c*128 + h*32 + cc]   (inline, per node)
    float qe = 0.f;
    const float* werow = We + (size_t)c * D + hb;
#pragma unroll
    for (int cc = 0; cc < 32; ++cc)
        qe = fmaf(__shfl(qd, lsrc + cc, 64), werow[cc], qe);

    const int i0 = rowptr[n], i1 = rowptr[n + 1];
    float acc = 0.f, sacc = 0.f, den = 0.f;

    int eid_n = 0, src_n = 0;
    if (i0 < i1) { eid_n = eids[i0]; src_n = srcs[i0]; }

    for (int i = i0; i < i1; ++i) {
        const int eid = eid_n, src = src_n;
        if (i + 1 < i1) { eid_n = eids[i + 1]; src_n = srcs[i + 1]; }

        const float ea = EA[(size_t)eid * EDIM + c];
        const float kd = K[(size_t)src * D + d];
        const float vd = V[(size_t)src * D + d];

        float p = fmaf(qd, kd, ea * qe);
#pragma unroll
        for (int off = 16; off; off >>= 1) p += __shfl_xor(p, off, 64);

        const float ex = expf(p * 0.17677669529663689f);  // 1/sqrt(32)
        den += ex;
        acc  = fmaf(ex, vd, acc);
        sacc = fmaf(ex, ea, sacc);   // s[h, k=c] += ex * ea_k
    }

    // correction: sum_k s[h,k] * We[k, d]
    float corr = 0.f;
#pragma unroll
    for (int k = 0; k < 32; ++k)
        corr = fmaf(__shfl(sacc, lsrc + k, 64), wcol[k], corr);

    const size_t o = (size_t)n * D + d;
    S[o] = (acc + corr) / (den + 1e-16f) + S[o];   // + skip, in place
}

// ---------------------------------------------------------------------------
// MLP layer 1: h1 = gelu(S @ W1 + b1)   (S already holds combined out)
// ---------------------------------------------------------------------------
__global__ __launch_bounds__(256) void mlp1_kernel(
    const float* __restrict__ S,
    const float* __restrict__ W1, const float* __restrict__ b1,
    float* __restrict__ H1, int N)
{
    const int row0 = blockIdx.x * TILE_M;
    __shared__ float sA[TILE_M * KCH];
    __shared__ float sB[KCH * D];

    const int t = threadIdx.x;
    const int c = t & 127;
    const int rbase = (t >> 7) * 32;

    float acc[32];
#pragma unroll
    for (int r = 0; r < 32; ++r) acc[r] = 0.f;

    for (int kk = 0; kk < D; kk += KCH) {
#pragma unroll
        for (int i = 0; i < 8; ++i) {
            int idx = t + i * 256;
            int r = idx >> 5, k = idx & 31;
            int gr = row0 + r;
            sA[idx] = (gr < N) ? S[gr * D + kk + k] : 0.f;
        }
#pragma unroll
        for (int i = 0; i < 16; ++i) {
            int idx = t + i * 256;
            sB[idx] = W1[(kk + (idx >> 7)) * D + (idx & 127)];
        }
        __syncthreads();
#pragma unroll
        for (int k4 = 0; k4 < 8; ++k4) {
            float w0 = sB[(k4 * 4 + 0) * D + c];
            float w1 = sB[(k4 * 4 + 1) * D + c];
            float w2 = sB[(k4 * 4 + 2) * D + c];
            float w3 = sB[(k4 * 4 + 3) * D + c];
#pragma unroll
            for (int r = 0; r < 32; ++r) {
                const float4 a = *reinterpret_cast<const float4*>(
                    &sA[(rbase + r) * KCH + k4 * 4]);
                acc[r] = fmaf(a.x, w0, fmaf(a.y, w1, fmaf(a.z, w2, fmaf(a.w, w3, acc[r]))));
            }
        }
        __syncthreads();
    }

    const float bias = b1[c];
#pragma unroll
    for (int r = 0; r < 32; ++r) {
        int gr = row0 + rbase + r;
        if (gr < N) H1[gr * D + c] = gelu_tanh(acc[r] + bias);
    }
}

// ---------------------------------------------------------------------------
// MLP layer 2 + residual: final = S + gelu(h1@W2+b2)
// ---------------------------------------------------------------------------
__global__ __launch_bounds__(256) void mlp2_kernel(
    const float* __restrict__ H1, const float* __restrict__ S,
    const float* __restrict__ W2, const float* __restrict__ b2,
    float* __restrict__ FINAL, int N)
{
    const int row0 = blockIdx.x * TILE_M;
    __shared__ float sA[TILE_M * KCH];
    __shared__ float sB[KCH * D];

    const int t = threadIdx.x;
    const int c = t & 127;
    const int rbase = (t >> 7) * 32;

    float acc[32];
#pragma unroll
    for (int r = 0; r < 32; ++r) acc[r] = 0.f;

    for (int kk = 0; kk < D; kk += KCH) {
#pragma unroll
        for (int i = 0; i < 8; ++i) {
            int idx = t + i * 256;
            int r = idx >> 5, k = idx & 31;
            int gr = row0 + r;
            sA[idx] = (gr < N) ? H1[gr * D + kk + k] : 0.f;
        }
#pragma unroll
        for (int i = 0; i < 16; ++i) {
            int idx = t + i * 256;
            sB[idx] = W2[(kk + (idx >> 7)) * D + (idx & 127)];
        }
        __syncthreads();
#pragma unroll
        for (int k4 = 0; k4 < 8; ++k4) {
            float w0 = sB[(k4 * 4 + 0) * D + c];
            float w1 = sB[(k4 * 4 + 1) * D + c];
            float w2 = sB[(k4 * 4 + 2) * D + c];
            float w3 = sB[(k4 * 4 + 3) * D + c];
#pragma unroll
            for (int r = 0; r < 32; ++r) {
                const float4 a = *reinterpret_cast<const float4*>(
                    &sA[(rbase + r) * KCH + k4 * 4]);
                acc[r] = fmaf(a.x, w0, fmaf(a.y, w1, fmaf(a.z, w2, fmaf(a.w, w3, acc[r]))));
            }
        }
        __syncthreads();
    }

    const float bias = b2[c];
#pragma unroll
    for (int r = 0; r < 32; ++r) {
        int gr = row0 + rbase + r;
        if (gr < N) FINAL[gr * D + c] = S[gr * D + c] + gelu_tanh(acc[r] + bias);
    }
}

// ---------------------------------------------------------------------------
extern "C" void kernel_launch(void* const* d_in, const int* in_sizes, int n_in,
                              void* d_out, int out_size, void* d_ws, size_t ws_size,
                              hipStream_t stream)
{
    const float* x   = (const float*)d_in[0];
    const int*   EI  = (const int*)  d_in[1];
    const float* EA  = (const float*)d_in[2];
    const float* Wq  = (const float*)d_in[3];
    const float* bq  = (const float*)d_in[4];
    const float* Wk  = (const float*)d_in[5];
    const float* bk  = (const float*)d_in[6];
    const float* Wv  = (const float*)d_in[7];
    const float* bv  = (const float*)d_in[8];
    const float* We  = (const float*)d_in[9];
    const float* Wsk = (const float*)d_in[10];
    const float* bsk = (const float*)d_in[11];
    const float* W1  = (const float*)d_in[12];
    const float* b1  = (const float*)d_in[13];
    const float* W2  = (const float*)d_in[14];
    const float* b2  = (const float*)d_in[15];

    const int N = in_sizes[0] / D;
    const int E = in_sizes[1] / 2;

    float* ws = (float*)d_ws;
    float* Qb = ws;                       // N*D
    float* Kb = Qb + (size_t)N * D;
    float* Vb = Kb + (size_t)N * D;
    float* Sb = Vb + (size_t)N * D;       // skip -> combined out
    float* H1b = Qb;                      // alias: Q dead after gather_pass

    int* ib      = (int*)(Sb + (size_t)N * D);
    int* deg     = ib;                    // N
    int* rowptr  = deg + N;               // N+1
    int* cursor  = rowptr + N + 1;        // N
    int* eidsb   = cursor + N;            // E
    int* srcsb   = eidsb + E;             // E

    hipMemsetAsync(deg, 0, (size_t)N * sizeof(int), stream);

    const int NB = (N + TILE_M - 1) / TILE_M;
    const int EB = (E + 255) / 256;

    gemm_qkvs<<<dim3(NB, 4), 256, 0, stream>>>(
        x, Wq, bq, Wk, bk, Wv, bv, Wsk, bsk, Qb, Kb, Vb, Sb, N);

    hist_kernel<<<EB, 256, 0, stream>>>(EI, deg, E);
    scan_kernel<<<1, 1024, 0, stream>>>(deg, rowptr, N);
    hipMemcpyAsync(cursor, rowptr, (size_t)N * sizeof(int),
                   hipMemcpyDeviceToDevice, stream);
    scatter_kernel<<<EB, 256, 0, stream>>>(EI, cursor, eidsb, srcsb, E);

    gather_pass<<<(N + 1) / 2, 256, 0, stream>>>(
        rowptr, eidsb, srcsb, EA, We, Qb, Kb, Vb, Sb, N);

    mlp1_kernel<<<NB, 256, 0, stream>>>(Sb, W1, b1, H1b, N);
    mlp2_kernel<<<NB, 256, 0, stream>>>(H1b, Sb, W2, b2, (float*)d_out, N);
}

// Round 3
// 640.817 us; speedup vs baseline: 1.5753x; 1.5154x over previous
//
#include <hip/hip_runtime.h>
#include <math.h>

// ---------------------------------------------------------------------------
// GraphTransformerBlock: TransformerConv (4 heads x 32) + residual MLP.
// Round 3:
//  - all 6 GEMMs -> bf16 MFMA (16x16x32), weights pre-transposed to [col][k]
//  - edge_attr permuted into CSR order (bf16) during scatter -> gather streams
//  - Q/K/V stored bf16; gather edge loop software-pipelined 2-deep
// Softmax without max-subtraction (shift-invariant, |alpha| small).
// ---------------------------------------------------------------------------

#define D 128
#define EDIM 32

using bf16x8 = __attribute__((ext_vector_type(8))) short;
using f32x4  = __attribute__((ext_vector_type(4))) float;
using ushort8 = __attribute__((ext_vector_type(8))) unsigned short;

__device__ inline unsigned short f2bf(float f) {
    unsigned int u = __float_as_uint(f);
    u += 0x7FFFu + ((u >> 16) & 1u);          // round-to-nearest-even
    return (unsigned short)(u >> 16);
}
__device__ inline float bf2f(unsigned short h) {
    return __uint_as_float(((unsigned int)h) << 16);
}
__device__ inline float gelu_tanh(float x) {
    float x3 = x * x * x;
    float u = 0.7978845608028654f * (x + 0.044715f * x3);
    return 0.5f * x * (1.0f + tanhf(u));
}

// ---------------------------------------------------------------------------
// prep_wt: Wt[m][col][k] = bf16(W_m[k][col]),  m in {q,k,v,skip,1,2}
// grid: 6*16384/256 = 384 blocks
// ---------------------------------------------------------------------------
__global__ __launch_bounds__(256) void prep_wt(
    const float* __restrict__ Wq, const float* __restrict__ Wk,
    const float* __restrict__ Wv, const float* __restrict__ Wsk,
    const float* __restrict__ W1, const float* __restrict__ W2,
    unsigned short* __restrict__ Wt)
{
    int t = blockIdx.x * 256 + threadIdx.x;
    int m = t >> 14;
    int r = t & 16383;
    int col = r & 127, k = r >> 7;
    const float* W = (m == 0) ? Wq : (m == 1) ? Wk : (m == 2) ? Wv
                   : (m == 3) ? Wsk : (m == 4) ? W1 : W2;
    Wt[(size_t)m * 16384 + (size_t)col * 128 + k] = f2bf(W[(size_t)k * 128 + col]);
}

// ---------------------------------------------------------------------------
// MFMA GEMM building block: block = 256 thr = 4 waves, 64 rows/block.
// Wave w: rows row0..row0+15. A-frag: lane holds A[lane&15][(lane>>4)*8+j].
// B-frag: lane holds B[(lane>>4)*8+j][lane&15] = Wt[col][k] contiguous.
// C/D: col = lane&15, row = (lane>>4)*4 + reg.
// ---------------------------------------------------------------------------

// q/k/v/skip: stage x-frags once, loop over 4 weight matrices.
__global__ __launch_bounds__(256) void gemm_qkvs(
    const float* __restrict__ x, const unsigned short* __restrict__ Wt,
    const float* __restrict__ bq, const float* __restrict__ bk,
    const float* __restrict__ bv, const float* __restrict__ bs,
    unsigned short* __restrict__ Q, unsigned short* __restrict__ K,
    unsigned short* __restrict__ V, float* __restrict__ S, int N)
{
    const int lane = threadIdx.x & 63;
    const int w = threadIdx.x >> 6;
    const int row0 = blockIdx.x * 64 + w * 16;
    const int lrow = lane & 15;
    const int kb = (lane >> 4) * 8;

    bf16x8 af[4];
    {
        int ar = row0 + lrow; if (ar > N - 1) ar = N - 1;
        const float* xr = x + (size_t)ar * D + kb;
#pragma unroll
        for (int kf = 0; kf < 4; ++kf) {
            float4 p0 = *(const float4*)(xr + kf * 32);
            float4 p1 = *(const float4*)(xr + kf * 32 + 4);
            bf16x8 a;
            a[0] = (short)f2bf(p0.x); a[1] = (short)f2bf(p0.y);
            a[2] = (short)f2bf(p0.z); a[3] = (short)f2bf(p0.w);
            a[4] = (short)f2bf(p1.x); a[5] = (short)f2bf(p1.y);
            a[6] = (short)f2bf(p1.z); a[7] = (short)f2bf(p1.w);
            af[kf] = a;
        }
    }

#pragma unroll
    for (int m = 0; m < 4; ++m) {
        const unsigned short* Wm = Wt + (size_t)m * 16384;
        const float* bias = (m == 0) ? bq : (m == 1) ? bk : (m == 2) ? bv : bs;
        f32x4 acc[8];
#pragma unroll
        for (int n = 0; n < 8; ++n) acc[n] = (f32x4){0.f, 0.f, 0.f, 0.f};
#pragma unroll
        for (int n = 0; n < 8; ++n) {
            const unsigned short* wp = Wm + (size_t)(n * 16 + lrow) * 128 + kb;
#pragma unroll
            for (int kf = 0; kf < 4; ++kf) {
                bf16x8 bfr = *(const bf16x8*)(wp + kf * 32);
                acc[n] = __builtin_amdgcn_mfma_f32_16x16x32_bf16(af[kf], bfr, acc[n], 0, 0, 0);
            }
        }
        const int rbase = row0 + (lane >> 4) * 4;
#pragma unroll
        for (int n = 0; n < 8; ++n) {
            const int col = n * 16 + lrow;
            const float bb = bias[col];
#pragma unroll
            for (int i = 0; i < 4; ++i) {
                int r = rbase + i;
                if (r < N) {
                    float v = acc[n][i] + bb;
                    size_t o = (size_t)r * D + col;
                    if (m == 0) Q[o] = f2bf(v);
                    else if (m == 1) K[o] = f2bf(v);
                    else if (m == 2) V[o] = f2bf(v);
                    else S[o] = v;
                }
            }
        }
    }
}

// mlp1: h1 = bf16(gelu(S @ W1 + b1)),  A = S (fp32)
__global__ __launch_bounds__(256) void mlp1_kernel(
    const float* __restrict__ S, const unsigned short* __restrict__ Wt1,
    const float* __restrict__ b1, unsigned short* __restrict__ H1, int N)
{
    const int lane = threadIdx.x & 63;
    const int w = threadIdx.x >> 6;
    const int row0 = blockIdx.x * 64 + w * 16;
    const int lrow = lane & 15;
    const int kb = (lane >> 4) * 8;

    bf16x8 af[4];
    {
        int ar = row0 + lrow; if (ar > N - 1) ar = N - 1;
        const float* xr = S + (size_t)ar * D + kb;
#pragma unroll
        for (int kf = 0; kf < 4; ++kf) {
            float4 p0 = *(const float4*)(xr + kf * 32);
            float4 p1 = *(const float4*)(xr + kf * 32 + 4);
            bf16x8 a;
            a[0] = (short)f2bf(p0.x); a[1] = (short)f2bf(p0.y);
            a[2] = (short)f2bf(p0.z); a[3] = (short)f2bf(p0.w);
            a[4] = (short)f2bf(p1.x); a[5] = (short)f2bf(p1.y);
            a[6] = (short)f2bf(p1.z); a[7] = (short)f2bf(p1.w);
            af[kf] = a;
        }
    }
    f32x4 acc[8];
#pragma unroll
    for (int n = 0; n < 8; ++n) acc[n] = (f32x4){0.f, 0.f, 0.f, 0.f};
#pragma unroll
    for (int n = 0; n < 8; ++n) {
        const unsigned short* wp = Wt1 + (size_t)(n * 16 + lrow) * 128 + kb;
#pragma unroll
        for (int kf = 0; kf < 4; ++kf) {
            bf16x8 bfr = *(const bf16x8*)(wp + kf * 32);
            acc[n] = __builtin_amdgcn_mfma_f32_16x16x32_bf16(af[kf], bfr, acc[n], 0, 0, 0);
        }
    }
    const int rbase = row0 + (lane >> 4) * 4;
#pragma unroll
    for (int n = 0; n < 8; ++n) {
        const int col = n * 16 + lrow;
        const float bb = b1[col];
#pragma unroll
        for (int i = 0; i < 4; ++i) {
            int r = rbase + i;
            if (r < N) H1[(size_t)r * D + col] = f2bf(gelu_tanh(acc[n][i] + bb));
        }
    }
}

// mlp2: final = S + gelu(H1 @ W2 + b2),  A = H1 (bf16, direct frag loads)
__global__ __launch_bounds__(256) void mlp2_kernel(
    const unsigned short* __restrict__ H1, const float* __restrict__ S,
    const unsigned short* __restrict__ Wt2, const float* __restrict__ b2,
    float* __restrict__ FINAL, int N)
{
    const int lane = threadIdx.x & 63;
    const int w = threadIdx.x >> 6;
    const int row0 = blockIdx.x * 64 + w * 16;
    const int lrow = lane & 15;
    const int kb = (lane >> 4) * 8;

    bf16x8 af[4];
    {
        int ar = row0 + lrow; if (ar > N - 1) ar = N - 1;
        const unsigned short* xr = H1 + (size_t)ar * D + kb;
#pragma unroll
        for (int kf = 0; kf < 4; ++kf) af[kf] = *(const bf16x8*)(xr + kf * 32);
    }
    f32x4 acc[8];
#pragma unroll
    for (int n = 0; n < 8; ++n) acc[n] = (f32x4){0.f, 0.f, 0.f, 0.f};
#pragma unroll
    for (int n = 0; n < 8; ++n) {
        const unsigned short* wp = Wt2 + (size_t)(n * 16 + lrow) * 128 + kb;
#pragma unroll
        for (int kf = 0; kf < 4; ++kf) {
            bf16x8 bfr = *(const bf16x8*)(wp + kf * 32);
            acc[n] = __builtin_amdgcn_mfma_f32_16x16x32_bf16(af[kf], bfr, acc[n], 0, 0, 0);
        }
    }
    const int rbase = row0 + (lane >> 4) * 4;
#pragma unroll
    for (int n = 0; n < 8; ++n) {
        const int col = n * 16 + lrow;
        const float bb = b2[col];
#pragma unroll
        for (int i = 0; i < 4; ++i) {
            int r = rbase + i;
            if (r < N) {
                size_t o = (size_t)r * D + col;
                FINAL[o] = S[o] + gelu_tanh(acc[n][i] + bb);
            }
        }
    }
}

// ---------------------------------------------------------------------------
// CSR construction
// ---------------------------------------------------------------------------
__global__ __launch_bounds__(256) void hist_kernel(
    const int* __restrict__ EI, int* __restrict__ deg, int E)
{
    int e = blockIdx.x * 256 + threadIdx.x;
    if (e < E) atomicAdd(&deg[EI[E + e]], 1);
}

__global__ __launch_bounds__(1024) void scan_kernel(
    const int* __restrict__ deg, int* __restrict__ rowptr, int N)
{
    __shared__ int tmp[1024];
    __shared__ int carry_s;
    const int t = threadIdx.x;
    if (t == 0) { carry_s = 0; rowptr[0] = 0; }
    __syncthreads();
    for (int base = 0; base < N; base += 1024) {
        int v = (base + t < N) ? deg[base + t] : 0;
        tmp[t] = v;
        __syncthreads();
        for (int off = 1; off < 1024; off <<= 1) {
            int add = (t >= off) ? tmp[t - off] : 0;
            __syncthreads();
            tmp[t] += add;
            __syncthreads();
        }
        if (base + t < N) rowptr[base + t + 1] = tmp[t] + carry_s;
        __syncthreads();
        if (t == 0) carry_s += tmp[1023];
        __syncthreads();
    }
}

// scatter: CSR-order src list + edge_attr permuted into CSR order (bf16)
__global__ __launch_bounds__(256) void scatter_kernel(
    const int* __restrict__ EI, const float* __restrict__ EA,
    int* __restrict__ cursor, int* __restrict__ srcs,
    unsigned short* __restrict__ EAP, int E)
{
    int e = blockIdx.x * 256 + threadIdx.x;
    if (e >= E) return;
    int dst = EI[E + e];
    int pos = atomicAdd(&cursor[dst], 1);
    srcs[pos] = EI[e];
    const float4* s4 = (const float4*)(EA + (size_t)e * EDIM);
    unsigned short* op = EAP + (size_t)pos * EDIM;
#pragma unroll
    for (int j = 0; j < 4; ++j) {
        float4 a = s4[2 * j], b = s4[2 * j + 1];
        ushort8 u;
        u[0] = f2bf(a.x); u[1] = f2bf(a.y); u[2] = f2bf(a.z); u[3] = f2bf(a.w);
        u[4] = f2bf(b.x); u[5] = f2bf(b.y); u[6] = f2bf(b.z); u[7] = f2bf(b.w);
        *(ushort8*)(op + j * 8) = u;
    }
}

// ---------------------------------------------------------------------------
// gather: 128 threads per dst node (2 nodes / block), 2-deep pipeline.
// S += (acc + We^T sacc) / den   (skip already in S)
// ---------------------------------------------------------------------------
__global__ __launch_bounds__(256) void gather_pass(
    const int* __restrict__ rowptr, const int* __restrict__ srcs,
    const unsigned short* __restrict__ EAP, const float* __restrict__ We,
    const unsigned short* __restrict__ Q, const unsigned short* __restrict__ K,
    const unsigned short* __restrict__ V, float* __restrict__ S, int N)
{
    const int t = threadIdx.x;
    const int d = t & 127;
    const int slot = t >> 7;
    const int n = blockIdx.x * 2 + slot;
    if (n >= N) return;
    const int c = d & 31;
    const int hb = d & 96;
    const int lsrc = d & 32;

    const float qd = bf2f(Q[(size_t)n * D + d]);

    // QE[h,c] = sum_cc q[h,cc] * We[c][h*32+cc]
    float qe = 0.f;
    const float* werow = We + (size_t)c * D + hb;
#pragma unroll
    for (int cc = 0; cc < 32; ++cc)
        qe = fmaf(__shfl(qd, lsrc + cc, 64), werow[cc], qe);

    const int i0 = rowptr[n], i1 = rowptr[n + 1];
    float acc = 0.f, sacc = 0.f, den = 0.f;

    float kd_c = 0.f, vd_c = 0.f, ea_c = 0.f;
    int src_n = 0;
    if (i0 < i1) {
        int s0 = srcs[i0];
        kd_c = bf2f(K[(size_t)s0 * D + d]);
        vd_c = bf2f(V[(size_t)s0 * D + d]);
        ea_c = bf2f(EAP[(size_t)i0 * EDIM + c]);
        if (i0 + 1 < i1) src_n = srcs[i0 + 1];
    }

    for (int i = i0; i < i1; ++i) {
        const float kd = kd_c, vd = vd_c, ea = ea_c;
        if (i + 1 < i1) {
            kd_c = bf2f(K[(size_t)src_n * D + d]);
            vd_c = bf2f(V[(size_t)src_n * D + d]);
            ea_c = bf2f(EAP[(size_t)(i + 1) * EDIM + c]);
            if (i + 2 < i1) src_n = srcs[i + 2];
        }
        float p = fmaf(qd, kd, ea * qe);
#pragma unroll
        for (int off = 16; off; off >>= 1) p += __shfl_xor(p, off, 64);
        const float ex = __expf(p * 0.17677669529663689f);   // 1/sqrt(32)
        den += ex;
        acc  = fmaf(ex, vd, acc);
        sacc = fmaf(ex, ea, sacc);
    }

    float corr = 0.f;
#pragma unroll
    for (int k = 0; k < 32; ++k)
        corr = fmaf(__shfl(sacc, lsrc + k, 64), We[(size_t)k * D + d], corr);

    const size_t o = (size_t)n * D + d;
    S[o] = (acc + corr) / (den + 1e-16f) + S[o];
}

// ---------------------------------------------------------------------------
extern "C" void kernel_launch(void* const* d_in, const int* in_sizes, int n_in,
                              void* d_out, int out_size, void* d_ws, size_t ws_size,
                              hipStream_t stream)
{
    const float* x   = (const float*)d_in[0];
    const int*   EI  = (const int*)  d_in[1];
    const float* EA  = (const float*)d_in[2];
    const float* Wq  = (const float*)d_in[3];
    const float* bq  = (const float*)d_in[4];
    const float* Wk  = (const float*)d_in[5];
    const float* bk  = (const float*)d_in[6];
    const float* Wv  = (const float*)d_in[7];
    const float* bv  = (const float*)d_in[8];
    const float* We  = (const float*)d_in[9];
    const float* Wsk = (const float*)d_in[10];
    const float* bsk = (const float*)d_in[11];
    const float* W1  = (const float*)d_in[12];
    const float* b1  = (const float*)d_in[13];
    const float* W2  = (const float*)d_in[14];
    const float* b2  = (const float*)d_in[15];

    const int N = in_sizes[0] / D;
    const int E = in_sizes[1] / 2;

    char* p = (char*)d_ws;
    auto alloc = [&](size_t bytes) -> void* {
        void* r = (void*)p;
        p += (bytes + 255) & ~(size_t)255;
        return r;
    };
    float*          Sb     = (float*)         alloc((size_t)N * D * 4);
    unsigned short* Qb     = (unsigned short*)alloc((size_t)N * D * 2);
    unsigned short* Kb     = (unsigned short*)alloc((size_t)N * D * 2);
    unsigned short* Vb     = (unsigned short*)alloc((size_t)N * D * 2);
    unsigned short* H1b    = (unsigned short*)alloc((size_t)N * D * 2);
    unsigned short* Wt     = (unsigned short*)alloc((size_t)6 * 16384 * 2);
    unsigned short* EAPb   = (unsigned short*)alloc((size_t)E * EDIM * 2);
    int*            srcsb  = (int*)           alloc((size_t)E * 4);
    int*            deg    = (int*)           alloc((size_t)N * 4);
    int*            rowptr = (int*)           alloc((size_t)(N + 1) * 4);
    int*            cursor = (int*)           alloc((size_t)N * 4);

    hipMemsetAsync(deg, 0, (size_t)N * sizeof(int), stream);

    const int NB = (N + 63) / 64;
    const int EB = (E + 255) / 256;

    prep_wt<<<(6 * 16384) / 256, 256, 0, stream>>>(Wq, Wk, Wv, Wsk, W1, W2, Wt);

    gemm_qkvs<<<NB, 256, 0, stream>>>(x, Wt, bq, bk, bv, bsk, Qb, Kb, Vb, Sb, N);

    hist_kernel<<<EB, 256, 0, stream>>>(EI, deg, E);
    scan_kernel<<<1, 1024, 0, stream>>>(deg, rowptr, N);
    hipMemcpyAsync(cursor, rowptr, (size_t)N * sizeof(int),
                   hipMemcpyDeviceToDevice, stream);
    scatter_kernel<<<EB, 256, 0, stream>>>(EI, EA, cursor, srcsb, EAPb, E);

    gather_pass<<<(N + 1) / 2, 256, 0, stream>>>(
        rowptr, srcsb, EAPb, We, Qb, Kb, Vb, Sb, N);

    mlp1_kernel<<<NB, 256, 0, stream>>>(Sb, Wt + (size_t)4 * 16384, b1, H1b, N);
    mlp2_kernel<<<NB, 256, 0, stream>>>(H1b, Sb, Wt + (size_t)5 * 16384, b2,
                                        (float*)d_out, N);
}

// Round 4
// 464.504 us; speedup vs baseline: 2.1732x; 1.3796x over previous
//
#include <hip/hip_runtime.h>
#include <math.h>

// ---------------------------------------------------------------------------
// GraphTransformerBlock: TransformerConv (4 heads x 32) + residual MLP.
// Round 4:
//  - gather: 1 wave/node, 4 edges in flight (4x16 lanes), DPP quad reduce
//    (no ds_bpermute in the edge loop), QE hoisted into the QKV MFMA GEMM,
//    edge-lift correction deferred to an MFMA combine fused with mlp1.
//  - hierarchical scan (3 tiny kernels) replaces the single-block scan.
// Softmax without max-subtraction (shift-invariant, |alpha| small).
// ---------------------------------------------------------------------------

#define D 128
#define EDIM 32

using bf16x8 = __attribute__((ext_vector_type(8))) short;
using f32x4  = __attribute__((ext_vector_type(4))) float;
using ushort8 = __attribute__((ext_vector_type(8))) unsigned short;

__device__ inline unsigned short f2bf(float f) {
    unsigned int u = __float_as_uint(f);
    u += 0x7FFFu + ((u >> 16) & 1u);          // round-to-nearest-even
    return (unsigned short)(u >> 16);
}
__device__ inline float bf2f(unsigned short h) {
    return __uint_as_float(((unsigned int)h) << 16);
}
__device__ inline float gelu_fast(float x) {
    float x3 = x * x * x;
    float u = 0.7978845608028654f * (x + 0.044715f * x3);
    // tanh(u) = 1 - 2/(exp(2u)+1)
    float t = 1.f - 2.f / (__expf(2.f * u) + 1.f);
    return 0.5f * x * (1.f + t);
}
// sum over aligned 4-lane quad via DPP quad_perm (all 4 lanes get the sum)
__device__ inline float quad_add(float x) {
    int a = __builtin_amdgcn_update_dpp(0, __float_as_int(x), 0xB1, 0xF, 0xF, true);
    x += __int_as_float(a);
    a = __builtin_amdgcn_update_dpp(0, __float_as_int(x), 0x4E, 0xF, 0xF, true);
    x += __int_as_float(a);
    return x;
}

// ---------------------------------------------------------------------------
// prep0: WqE = Wq @ WE3, bqE = bq @ WE3, with WE3[h*32+c, h*32+k] = We[k,h*32+c]
// 1 block x 128 threads (thread = output col j = h*32+k)
// ---------------------------------------------------------------------------
__global__ __launch_bounds__(128) void prep0(
    const float* __restrict__ Wq, const float* __restrict__ bq,
    const float* __restrict__ We, float* __restrict__ WqE,
    float* __restrict__ bqE)
{
    const int j = threadIdx.x;            // h*32 + k
    const int h = j >> 5, k = j & 31;
    const float* wek = We + (size_t)k * D + h * 32;   // We[k][h*32 + c]
    float s = 0.f;
#pragma unroll 8
    for (int c = 0; c < 32; ++c) s = fmaf(bq[h * 32 + c], wek[c], s);
    bqE[j] = s;
    for (int dp = 0; dp < 128; ++dp) {
        const float* wqr = Wq + (size_t)dp * D + h * 32;
        float s2 = 0.f;
#pragma unroll 8
        for (int c = 0; c < 32; ++c) s2 = fmaf(wqr[c], wek[c], s2);
        WqE[(size_t)dp * D + j] = s2;
    }
}

// ---------------------------------------------------------------------------
// prep_wt: 8 bf16 weight tables in MFMA-B layout Wt[m][col][kk] = W_m[kk][col]
//   m: 0=Wq 1=Wk 2=Wv 3=Wskip 4=W1 5=W2 6=WqE 7=WtCorr(block-diag of We)
// ---------------------------------------------------------------------------
__global__ __launch_bounds__(256) void prep_wt(
    const float* __restrict__ Wq, const float* __restrict__ Wk,
    const float* __restrict__ Wv, const float* __restrict__ Wsk,
    const float* __restrict__ W1, const float* __restrict__ W2,
    const float* __restrict__ WqE, const float* __restrict__ We,
    unsigned short* __restrict__ Wt)
{
    int t = blockIdx.x * 256 + threadIdx.x;
    int m = t >> 14;
    int r = t & 16383;
    int col = r & 127, kk = r >> 7;
    float v;
    if (m < 6) {
        const float* W = (m == 0) ? Wq : (m == 1) ? Wk : (m == 2) ? Wv
                       : (m == 3) ? Wsk : (m == 4) ? W1 : W2;
        v = W[(size_t)kk * D + col];
    } else if (m == 6) {
        v = WqE[(size_t)kk * D + col];
    } else {
        // corr GEMM B: B[j=h*32+k][d=h*32+c] = We[k][d] if same head else 0
        v = ((kk >> 5) == (col >> 5)) ? We[(size_t)(kk & 31) * D + col] : 0.f;
    }
    Wt[(size_t)m * 16384 + (size_t)col * 128 + kk] = f2bf(v);
}

// ---------------------------------------------------------------------------
// gemm_qkvs: 5 outputs off one A-frag set: Q,K,V (bf16), skip (f32), QE (f32)
// ---------------------------------------------------------------------------
__global__ __launch_bounds__(256) void gemm_qkvs(
    const float* __restrict__ x, const unsigned short* __restrict__ Wt,
    const float* __restrict__ bq, const float* __restrict__ bk,
    const float* __restrict__ bv, const float* __restrict__ bs,
    const float* __restrict__ bqE,
    unsigned short* __restrict__ Q, unsigned short* __restrict__ K,
    unsigned short* __restrict__ V, float* __restrict__ S,
    float* __restrict__ QE, int N)
{
    const int lane = threadIdx.x & 63;
    const int w = threadIdx.x >> 6;
    const int row0 = blockIdx.x * 64 + w * 16;
    const int lrow = lane & 15;
    const int kb = (lane >> 4) * 8;
    const int rq = (lane >> 4) * 4;

    bf16x8 af[4];
    {
        int ar = row0 + lrow; if (ar > N - 1) ar = N - 1;
        const float* xr = x + (size_t)ar * D + kb;
#pragma unroll
        for (int kf = 0; kf < 4; ++kf) {
            float4 p0 = *(const float4*)(xr + kf * 32);
            float4 p1 = *(const float4*)(xr + kf * 32 + 4);
            bf16x8 a;
            a[0] = (short)f2bf(p0.x); a[1] = (short)f2bf(p0.y);
            a[2] = (short)f2bf(p0.z); a[3] = (short)f2bf(p0.w);
            a[4] = (short)f2bf(p1.x); a[5] = (short)f2bf(p1.y);
            a[6] = (short)f2bf(p1.z); a[7] = (short)f2bf(p1.w);
            af[kf] = a;
        }
    }

#pragma unroll
    for (int m = 0; m < 5; ++m) {
        const int widx = (m < 4) ? m : 6;
        const unsigned short* Wm = Wt + (size_t)widx * 16384;
        const float* bias = (m == 0) ? bq : (m == 1) ? bk : (m == 2) ? bv
                          : (m == 3) ? bs : bqE;
        f32x4 acc[8];
#pragma unroll
        for (int nf = 0; nf < 8; ++nf) acc[nf] = (f32x4){0.f, 0.f, 0.f, 0.f};
#pragma unroll
        for (int nf = 0; nf < 8; ++nf) {
            const unsigned short* wp = Wm + (size_t)(nf * 16 + lrow) * 128 + kb;
#pragma unroll
            for (int kf = 0; kf < 4; ++kf) {
                bf16x8 bfr = *(const bf16x8*)(wp + kf * 32);
                acc[nf] = __builtin_amdgcn_mfma_f32_16x16x32_bf16(af[kf], bfr, acc[nf], 0, 0, 0);
            }
        }
#pragma unroll
        for (int nf = 0; nf < 8; ++nf) {
            const int col = nf * 16 + lrow;
            const float bb = bias[col];
#pragma unroll
            for (int i = 0; i < 4; ++i) {
                int r = row0 + rq + i;
                if (r < N) {
                    float v = acc[nf][i] + bb;
                    size_t o = (size_t)r * D + col;
                    if (m == 0) Q[o] = f2bf(v);
                    else if (m == 1) K[o] = f2bf(v);
                    else if (m == 2) V[o] = f2bf(v);
                    else if (m == 3) S[o] = v;
                    else QE[o] = v;
                }
            }
        }
    }
}

// ---------------------------------------------------------------------------
// CSR construction: hist -> hierarchical scan -> scatter (srcs + bf16 EA perm)
// ---------------------------------------------------------------------------
__global__ __launch_bounds__(256) void hist_kernel(
    const int* __restrict__ EI, int* __restrict__ deg, int E)
{
    int e = blockIdx.x * 256 + threadIdx.x;
    if (e < E) atomicAdd(&deg[EI[E + e]], 1);
}

__global__ __launch_bounds__(1024) void scanA(
    const int* __restrict__ deg, int* __restrict__ rowptr,
    int* __restrict__ psums, int N)
{
    __shared__ int tmp[1024];
    const int t = threadIdx.x;
    const int i = blockIdx.x * 1024 + t;
    int v = (i < N) ? deg[i] : 0;
    tmp[t] = v;
    __syncthreads();
    for (int off = 1; off < 1024; off <<= 1) {
        int add = (t >= off) ? tmp[t - off] : 0;
        __syncthreads();
        tmp[t] += add;
        __syncthreads();
    }
    if (i < N) rowptr[i + 1] = tmp[t];
    if (t == 1023) psums[blockIdx.x] = tmp[1023];
}

__global__ __launch_bounds__(1024) void scanB(int* __restrict__ psums, int nb)
{
    __shared__ int tmp[1024];
    const int t = threadIdx.x;
    int v = (t < nb) ? psums[t] : 0;
    tmp[t] = v;
    __syncthreads();
    for (int off = 1; off < 1024; off <<= 1) {
        int add = (t >= off) ? tmp[t - off] : 0;
        __syncthreads();
        tmp[t] += add;
        __syncthreads();
    }
    if (t < nb) psums[t] = tmp[t] - v;   // exclusive
}

__global__ __launch_bounds__(256) void scanC(
    int* __restrict__ rowptr, int* __restrict__ cursor,
    const int* __restrict__ psums, int N)
{
    int i = blockIdx.x * 256 + threadIdx.x;
    if (i == 0) { rowptr[0] = 0; cursor[0] = 0; }
    if (i < N) {
        int val = rowptr[i + 1] + psums[i >> 10];
        rowptr[i + 1] = val;
        if (i + 1 < N) cursor[i + 1] = val;
    }
}

__global__ __launch_bounds__(256) void scatter_kernel(
    const int* __restrict__ EI, const float* __restrict__ EA,
    int* __restrict__ cursor, int* __restrict__ srcs,
    unsigned short* __restrict__ EAP, int E)
{
    int e = blockIdx.x * 256 + threadIdx.x;
    if (e >= E) return;
    int dst = EI[E + e];
    int pos = atomicAdd(&cursor[dst], 1);
    srcs[pos] = EI[e];
    const float4* s4 = (const float4*)(EA + (size_t)e * EDIM);
    unsigned short* op = EAP + (size_t)pos * EDIM;
#pragma unroll
    for (int j = 0; j < 4; ++j) {
        float4 a = s4[2 * j], b = s4[2 * j + 1];
        ushort8 u;
        u[0] = f2bf(a.x); u[1] = f2bf(a.y); u[2] = f2bf(a.z); u[3] = f2bf(a.w);
        u[4] = f2bf(b.x); u[5] = f2bf(b.y); u[6] = f2bf(b.z); u[7] = f2bf(b.w);
        *(ushort8*)(op + j * 8) = u;
    }
}

// ---------------------------------------------------------------------------
// gather: 1 wave per node; 4 edge groups x 16 lanes (lane owns 8 dims).
// alpha reduce = 2 DPP ops within the head's aligned quad.
// Writes (in place into SB): preout = sum(ex*v)/den + skip
// and SAS (bf16) = sum(ex*ea)/den  -> corr GEMM later.
// ---------------------------------------------------------------------------
__global__ __launch_bounds__(256) void gather_pass(
    const int* __restrict__ rowptr, const int* __restrict__ srcs,
    const unsigned short* __restrict__ EAP,
    const unsigned short* __restrict__ Q, const unsigned short* __restrict__ K,
    const unsigned short* __restrict__ V, const float* __restrict__ QE,
    float* __restrict__ SB, unsigned short* __restrict__ SAS, int N)
{
    const int lane = threadIdx.x & 63;
    const int wid = threadIdx.x >> 6;
    const int n = blockIdx.x * 4 + wid;
    if (n >= N) return;
    const int g = lane & 15;        // dim slice: d = g*8..+8 (head g/4)
    const int grp = lane >> 4;      // edge group 0..3

    float q8[8], qe8[8];
    {
        bf16x8 qb = *(const bf16x8*)(Q + (size_t)n * D + g * 8);
#pragma unroll
        for (int j = 0; j < 8; ++j) q8[j] = bf2f((unsigned short)qb[j]);
        float4 a = *(const float4*)(QE + (size_t)n * D + g * 8);
        float4 b = *(const float4*)(QE + (size_t)n * D + g * 8 + 4);
        qe8[0] = a.x; qe8[1] = a.y; qe8[2] = a.z; qe8[3] = a.w;
        qe8[4] = b.x; qe8[5] = b.y; qe8[6] = b.z; qe8[7] = b.w;
    }

    float acc[8], sa[8], den = 0.f;
#pragma unroll
    for (int j = 0; j < 8; ++j) { acc[j] = 0.f; sa[j] = 0.f; }

    const int i0 = rowptr[n], i1 = rowptr[n + 1];

    int idx = i0 + grp;
    int src_c = (idx < i1) ? srcs[idx] : -1;

    for (int base = i0; base < i1; base += 4, idx += 4) {
        const int src = src_c;
        {
            int idx_n = idx + 4;
            src_c = (idx_n < i1) ? srcs[idx_n] : -1;
        }
        bf16x8 kb = {0,0,0,0,0,0,0,0};
        bf16x8 vb = {0,0,0,0,0,0,0,0};
        bf16x8 eb = {0,0,0,0,0,0,0,0};
        if (src >= 0) {
            kb = *(const bf16x8*)(K + (size_t)src * D + g * 8);
            vb = *(const bf16x8*)(V + (size_t)src * D + g * 8);
            eb = *(const bf16x8*)(EAP + (size_t)idx * EDIM + (g & 3) * 8);
        }
        float ef[8], vf[8];
        float p = 0.f;
#pragma unroll
        for (int j = 0; j < 8; ++j) {
            float kf = bf2f((unsigned short)kb[j]);
            ef[j] = bf2f((unsigned short)eb[j]);
            vf[j] = bf2f((unsigned short)vb[j]);
            p = fmaf(q8[j], kf, fmaf(ef[j], qe8[j], p));
        }
        p = quad_add(p);                      // full 32-dim dot for this head
        float ex = (src >= 0) ? __expf(p * 0.17677669529663689f) : 0.f;
        den += ex;
#pragma unroll
        for (int j = 0; j < 8; ++j) {
            acc[j] = fmaf(ex, vf[j], acc[j]);
            sa[j]  = fmaf(ex, ef[j], sa[j]);
        }
    }

    // combine the 4 edge groups (once per node)
#pragma unroll
    for (int off = 16; off <= 32; off <<= 1) {
        den += __shfl_xor(den, off, 64);
#pragma unroll
        for (int j = 0; j < 8; ++j) {
            acc[j] += __shfl_xor(acc[j], off, 64);
            sa[j]  += __shfl_xor(sa[j],  off, 64);
        }
    }

    if (grp == 0) {
        const float rden = 1.f / (den + 1e-16f);
        float* so = SB + (size_t)n * D + g * 8;
        unsigned short* po = SAS + (size_t)n * D + g * 8;
#pragma unroll
        for (int j = 0; j < 8; ++j) {
            so[j] = fmaf(acc[j], rden, so[j]);    // + skip (in place)
            po[j] = f2bf(sa[j] * rden);
        }
    }
}

// ---------------------------------------------------------------------------
// combine_mlp1: OUT = preout + SAS @ WtCorr (MFMA, C-init = preout);
// then H1 = gelu(OUT @ W1 + b1) via LDS bounce. OUT written in place into SB.
// ---------------------------------------------------------------------------
__global__ __launch_bounds__(256) void combine_mlp1(
    float* __restrict__ SB, const unsigned short* __restrict__ SAS,
    const unsigned short* __restrict__ WtC, const unsigned short* __restrict__ Wt1,
    const float* __restrict__ b1, unsigned short* __restrict__ H1, int N)
{
    __shared__ float lds[64 * 132];
    const int lane = threadIdx.x & 63;
    const int w = threadIdx.x >> 6;
    const int row0 = blockIdx.x * 64 + w * 16;
    const int lrow = lane & 15;
    const int kb = (lane >> 4) * 8;
    const int rq = (lane >> 4) * 4;

    bf16x8 af[4];
    {
        int ar = row0 + lrow; if (ar > N - 1) ar = N - 1;
        const unsigned short* xr = SAS + (size_t)ar * D + kb;
#pragma unroll
        for (int kf = 0; kf < 4; ++kf) af[kf] = *(const bf16x8*)(xr + kf * 32);
    }
    f32x4 acc[8];
#pragma unroll
    for (int nf = 0; nf < 8; ++nf) {
        const int col = nf * 16 + lrow;
#pragma unroll
        for (int i = 0; i < 4; ++i) {
            int r = row0 + rq + i;
            acc[nf][i] = (r < N) ? SB[(size_t)r * D + col] : 0.f;
        }
    }
#pragma unroll
    for (int nf = 0; nf < 8; ++nf) {
        const unsigned short* wp = WtC + (size_t)(nf * 16 + lrow) * 128 + kb;
#pragma unroll
        for (int kf = 0; kf < 4; ++kf) {
            bf16x8 bfr = *(const bf16x8*)(wp + kf * 32);
            acc[nf] = __builtin_amdgcn_mfma_f32_16x16x32_bf16(af[kf], bfr, acc[nf], 0, 0, 0);
        }
    }
#pragma unroll
    for (int nf = 0; nf < 8; ++nf) {
        const int col = nf * 16 + lrow;
#pragma unroll
        for (int i = 0; i < 4; ++i) {
            int r = row0 + rq + i;
            lds[(w * 16 + rq + i) * 132 + col] = acc[nf][i];
            if (r < N) SB[(size_t)r * D + col] = acc[nf][i];   // OUT
        }
    }
    __syncthreads();
    bf16x8 af2[4];
#pragma unroll
    for (int kf = 0; kf < 4; ++kf) {
        const float* lr = &lds[(w * 16 + lrow) * 132 + kb + kf * 32];
#pragma unroll
        for (int j = 0; j < 8; ++j) af2[kf][j] = (short)f2bf(lr[j]);
    }
    f32x4 acc2[8];
#pragma unroll
    for (int nf = 0; nf < 8; ++nf) acc2[nf] = (f32x4){0.f, 0.f, 0.f, 0.f};
#pragma unroll
    for (int nf = 0; nf < 8; ++nf) {
        const unsigned short* wp = Wt1 + (size_t)(nf * 16 + lrow) * 128 + kb;
#pragma unroll
        for (int kf = 0; kf < 4; ++kf) {
            bf16x8 bfr = *(const bf16x8*)(wp + kf * 32);
            acc2[nf] = __builtin_amdgcn_mfma_f32_16x16x32_bf16(af2[kf], bfr, acc2[nf], 0, 0, 0);
        }
    }
#pragma unroll
    for (int nf = 0; nf < 8; ++nf) {
        const int col = nf * 16 + lrow;
        const float bb = b1[col];
#pragma unroll
        for (int i = 0; i < 4; ++i) {
            int r = row0 + rq + i;
            if (r < N) H1[(size_t)r * D + col] = f2bf(gelu_fast(acc2[nf][i] + bb));
        }
    }
}

// ---------------------------------------------------------------------------
// mlp2: FINAL = OUT + gelu(H1 @ W2 + b2)
// ---------------------------------------------------------------------------
__global__ __launch_bounds__(256) void mlp2_kernel(
    const unsigned short* __restrict__ H1, const float* __restrict__ OUT,
    const unsigned short* __restrict__ Wt2, const float* __restrict__ b2,
    float* __restrict__ FINAL, int N)
{
    const int lane = threadIdx.x & 63;
    const int w = threadIdx.x >> 6;
    const int row0 = blockIdx.x * 64 + w * 16;
    const int lrow = lane & 15;
    const int kb = (lane >> 4) * 8;
    const int rq = (lane >> 4) * 4;

    bf16x8 af[4];
    {
        int ar = row0 + lrow; if (ar > N - 1) ar = N - 1;
        const unsigned short* xr = H1 + (size_t)ar * D + kb;
#pragma unroll
        for (int kf = 0; kf < 4; ++kf) af[kf] = *(const bf16x8*)(xr + kf * 32);
    }
    f32x4 acc[8];
#pragma unroll
    for (int nf = 0; nf < 8; ++nf) acc[nf] = (f32x4){0.f, 0.f, 0.f, 0.f};
#pragma unroll
    for (int nf = 0; nf < 8; ++nf) {
        const unsigned short* wp = Wt2 + (size_t)(nf * 16 + lrow) * 128 + kb;
#pragma unroll
        for (int kf = 0; kf < 4; ++kf) {
            bf16x8 bfr = *(const bf16x8*)(wp + kf * 32);
            acc[nf] = __builtin_amdgcn_mfma_f32_16x16x32_bf16(af[kf], bfr, acc[nf], 0, 0, 0);
        }
    }
#pragma unroll
    for (int nf = 0; nf < 8; ++nf) {
        const int col = nf * 16 + lrow;
        const float bb = b2[col];
#pragma unroll
        for (int i = 0; i < 4; ++i) {
            int r = row0 + rq + i;
            if (r < N) {
                size_t o = (size_t)r * D + col;
                FINAL[o] = OUT[o] + gelu_fast(acc[nf][i] + bb);
            }
        }
    }
}

// ---------------------------------------------------------------------------
extern "C" void kernel_launch(void* const* d_in, const int* in_sizes, int n_in,
                              void* d_out, int out_size, void* d_ws, size_t ws_size,
                              hipStream_t stream)
{
    const float* x   = (const float*)d_in[0];
    const int*   EI  = (const int*)  d_in[1];
    const float* EA  = (const float*)d_in[2];
    const float* Wq  = (const float*)d_in[3];
    const float* bq  = (const float*)d_in[4];
    const float* Wk  = (const float*)d_in[5];
    const float* bk  = (const float*)d_in[6];
    const float* Wv  = (const float*)d_in[7];
    const float* bv  = (const float*)d_in[8];
    const float* We  = (const float*)d_in[9];
    const float* Wsk = (const float*)d_in[10];
    const float* bsk = (const float*)d_in[11];
    const float* W1  = (const float*)d_in[12];
    const float* b1  = (const float*)d_in[13];
    const float* W2  = (const float*)d_in[14];
    const float* b2  = (const float*)d_in[15];

    const int N = in_sizes[0] / D;
    const int E = in_sizes[1] / 2;

    char* p = (char*)d_ws;
    auto alloc = [&](size_t bytes) -> void* {
        void* r = (void*)p;
        p += (bytes + 255) & ~(size_t)255;
        return r;
    };
    float*          Sb     = (float*)         alloc((size_t)N * D * 4); // skip->preout->OUT
    float*          QEb    = (float*)         alloc((size_t)N * D * 4); // QE; later H1 (bf16)
    unsigned short* Qb     = (unsigned short*)alloc((size_t)N * D * 2);
    unsigned short* Kb     = (unsigned short*)alloc((size_t)N * D * 2);
    unsigned short* Vb     = (unsigned short*)alloc((size_t)N * D * 2);
    unsigned short* SASb   = (unsigned short*)alloc((size_t)N * D * 2);
    unsigned short* EAPb   = (unsigned short*)alloc((size_t)E * EDIM * 2);
    int*            srcsb  = (int*)           alloc((size_t)E * 4);
    unsigned short* Wt     = (unsigned short*)alloc((size_t)8 * 16384 * 2);
    float*          WqEb   = (float*)         alloc((size_t)128 * 128 * 4);
    float*          bqEb   = (float*)         alloc((size_t)128 * 4);
    int*            deg    = (int*)           alloc((size_t)N * 4);
    int*            rowptr = (int*)           alloc((size_t)(N + 1) * 4);
    int*            cursor = (int*)           alloc((size_t)(N + 1) * 4);
    int*            psums  = (int*)           alloc((size_t)1024 * 4);

    unsigned short* H1b = (unsigned short*)QEb;   // alias: QE dead after gather

    hipMemsetAsync(deg, 0, (size_t)N * sizeof(int), stream);

    const int NB = (N + 63) / 64;
    const int EB = (E + 255) / 256;
    const int SB_ = (N + 1023) / 1024;

    prep0<<<1, 128, 0, stream>>>(Wq, bq, We, WqEb, bqEb);
    prep_wt<<<(8 * 16384) / 256, 256, 0, stream>>>(Wq, Wk, Wv, Wsk, W1, W2,
                                                   WqEb, We, Wt);

    gemm_qkvs<<<NB, 256, 0, stream>>>(x, Wt, bq, bk, bv, bsk, bqEb,
                                      Qb, Kb, Vb, Sb, QEb, N);

    hist_kernel<<<EB, 256, 0, stream>>>(EI, deg, E);
    scanA<<<SB_, 1024, 0, stream>>>(deg, rowptr, psums, N);
    scanB<<<1, 1024, 0, stream>>>(psums, SB_);
    scanC<<<(N + 255) / 256, 256, 0, stream>>>(rowptr, cursor, psums, N);
    scatter_kernel<<<EB, 256, 0, stream>>>(EI, EA, cursor, srcsb, EAPb, E);

    gather_pass<<<(N + 3) / 4, 256, 0, stream>>>(
        rowptr, srcsb, EAPb, Qb, Kb, Vb, QEb, Sb, SASb, N);

    combine_mlp1<<<NB, 256, 0, stream>>>(Sb, SASb, Wt + (size_t)7 * 16384,
                                         Wt + (size_t)4 * 16384, b1, H1b, N);
    mlp2_kernel<<<NB, 256, 0, stream>>>(H1b, Sb, Wt + (size_t)5 * 16384, b2,
                                        (float*)d_out, N);
}

// Round 5
// 371.980 us; speedup vs baseline: 2.7138x; 1.2487x over previous
//
#include <hip/hip_runtime.h>
#include <math.h>

// ---------------------------------------------------------------------------
// GraphTransformerBlock: TransformerConv (4 heads x 32) + residual MLP.
// Round 5: kill the serial prep0 (113us on 1 CU!). WqE dot-products moved
// into prep_wt's m==6 branch (fully parallel); bqE is a 2us micro-kernel.
// Everything else unchanged from round 4.
// ---------------------------------------------------------------------------

#define D 128
#define EDIM 32

using bf16x8 = __attribute__((ext_vector_type(8))) short;
using f32x4  = __attribute__((ext_vector_type(4))) float;
using ushort8 = __attribute__((ext_vector_type(8))) unsigned short;

__device__ inline unsigned short f2bf(float f) {
    unsigned int u = __float_as_uint(f);
    u += 0x7FFFu + ((u >> 16) & 1u);          // round-to-nearest-even
    return (unsigned short)(u >> 16);
}
__device__ inline float bf2f(unsigned short h) {
    return __uint_as_float(((unsigned int)h) << 16);
}
__device__ inline float gelu_fast(float x) {
    float x3 = x * x * x;
    float u = 0.7978845608028654f * (x + 0.044715f * x3);
    float t = 1.f - 2.f / (__expf(2.f * u) + 1.f);   // tanh(u)
    return 0.5f * x * (1.f + t);
}
// sum over aligned 4-lane quad via DPP quad_perm (all 4 lanes get the sum)
__device__ inline float quad_add(float x) {
    int a = __builtin_amdgcn_update_dpp(0, __float_as_int(x), 0xB1, 0xF, 0xF, true);
    x += __int_as_float(a);
    a = __builtin_amdgcn_update_dpp(0, __float_as_int(x), 0x4E, 0xF, 0xF, true);
    x += __int_as_float(a);
    return x;
}

// ---------------------------------------------------------------------------
// prep_bqe: bqE[j] = sum_c bq[h*32+c] * We[k][h*32+c],  j = h*32+k
// ---------------------------------------------------------------------------
__global__ __launch_bounds__(128) void prep_bqe(
    const float* __restrict__ bq, const float* __restrict__ We,
    float* __restrict__ bqE)
{
    const int j = threadIdx.x;
    const int hb = j & 96, k = j & 31;
    const float* wek = We + (size_t)k * D + hb;
    float s = 0.f;
#pragma unroll 8
    for (int c = 0; c < 32; ++c) s = fmaf(bq[hb + c], wek[c], s);
    bqE[j] = s;
}

// ---------------------------------------------------------------------------
// prep_wt: 8 bf16 weight tables in MFMA-B layout Wt[m][col][kk] = W_m[kk][col]
//   m: 0=Wq 1=Wk 2=Wv 3=Wskip 4=W1 5=W2 6=WqE (computed inline) 7=WtCorr
// ---------------------------------------------------------------------------
__global__ __launch_bounds__(256) void prep_wt(
    const float* __restrict__ Wq, const float* __restrict__ Wk,
    const float* __restrict__ Wv, const float* __restrict__ Wsk,
    const float* __restrict__ W1, const float* __restrict__ W2,
    const float* __restrict__ We, unsigned short* __restrict__ Wt)
{
    int t = blockIdx.x * 256 + threadIdx.x;
    int m = t >> 14;
    int r = t & 16383;
    int col = r & 127, kk = r >> 7;
    float v;
    if (m < 6) {
        const float* W = (m == 0) ? Wq : (m == 1) ? Wk : (m == 2) ? Wv
                       : (m == 3) ? Wsk : (m == 4) ? W1 : W2;
        v = W[(size_t)kk * D + col];
    } else if (m == 6) {
        // WqE[kk][col] = sum_c Wq[kk][hb+c] * We[col&31][hb+c], hb=(col>>5)*32
        const int hb = col & 96;
        const float* wqr = Wq + (size_t)kk * D + hb;
        const float* wer = We + (size_t)(col & 31) * D + hb;
        float s = 0.f;
#pragma unroll 8
        for (int c = 0; c < 32; ++c) s = fmaf(wqr[c], wer[c], s);
        v = s;
    } else {
        // corr GEMM B: B[j=h*32+k][d=h*32+c] = We[k][d] if same head else 0
        v = ((kk >> 5) == (col >> 5)) ? We[(size_t)(kk & 31) * D + col] : 0.f;
    }
    Wt[(size_t)m * 16384 + (size_t)col * 128 + kk] = f2bf(v);
}

// ---------------------------------------------------------------------------
// gemm_qkvs: 5 outputs off one A-frag set: Q,K,V (bf16), skip (f32), QE (f32)
// ---------------------------------------------------------------------------
__global__ __launch_bounds__(256) void gemm_qkvs(
    const float* __restrict__ x, const unsigned short* __restrict__ Wt,
    const float* __restrict__ bq, const float* __restrict__ bk,
    const float* __restrict__ bv, const float* __restrict__ bs,
    const float* __restrict__ bqE,
    unsigned short* __restrict__ Q, unsigned short* __restrict__ K,
    unsigned short* __restrict__ V, float* __restrict__ S,
    float* __restrict__ QE, int N)
{
    const int lane = threadIdx.x & 63;
    const int w = threadIdx.x >> 6;
    const int row0 = blockIdx.x * 64 + w * 16;
    const int lrow = lane & 15;
    const int kb = (lane >> 4) * 8;
    const int rq = (lane >> 4) * 4;

    bf16x8 af[4];
    {
        int ar = row0 + lrow; if (ar > N - 1) ar = N - 1;
        const float* xr = x + (size_t)ar * D + kb;
#pragma unroll
        for (int kf = 0; kf < 4; ++kf) {
            float4 p0 = *(const float4*)(xr + kf * 32);
            float4 p1 = *(const float4*)(xr + kf * 32 + 4);
            bf16x8 a;
            a[0] = (short)f2bf(p0.x); a[1] = (short)f2bf(p0.y);
            a[2] = (short)f2bf(p0.z); a[3] = (short)f2bf(p0.w);
            a[4] = (short)f2bf(p1.x); a[5] = (short)f2bf(p1.y);
            a[6] = (short)f2bf(p1.z); a[7] = (short)f2bf(p1.w);
            af[kf] = a;
        }
    }

#pragma unroll
    for (int m = 0; m < 5; ++m) {
        const int widx = (m < 4) ? m : 6;
        const unsigned short* Wm = Wt + (size_t)widx * 16384;
        const float* bias = (m == 0) ? bq : (m == 1) ? bk : (m == 2) ? bv
                          : (m == 3) ? bs : bqE;
        f32x4 acc[8];
#pragma unroll
        for (int nf = 0; nf < 8; ++nf) acc[nf] = (f32x4){0.f, 0.f, 0.f, 0.f};
#pragma unroll
        for (int nf = 0; nf < 8; ++nf) {
            const unsigned short* wp = Wm + (size_t)(nf * 16 + lrow) * 128 + kb;
#pragma unroll
            for (int kf = 0; kf < 4; ++kf) {
                bf16x8 bfr = *(const bf16x8*)(wp + kf * 32);
                acc[nf] = __builtin_amdgcn_mfma_f32_16x16x32_bf16(af[kf], bfr, acc[nf], 0, 0, 0);
            }
        }
#pragma unroll
        for (int nf = 0; nf < 8; ++nf) {
            const int col = nf * 16 + lrow;
            const float bb = bias[col];
#pragma unroll
            for (int i = 0; i < 4; ++i) {
                int r = row0 + rq + i;
                if (r < N) {
                    float v = acc[nf][i] + bb;
                    size_t o = (size_t)r * D + col;
                    if (m == 0) Q[o] = f2bf(v);
                    else if (m == 1) K[o] = f2bf(v);
                    else if (m == 2) V[o] = f2bf(v);
                    else if (m == 3) S[o] = v;
                    else QE[o] = v;
                }
            }
        }
    }
}

// ---------------------------------------------------------------------------
// CSR construction: hist -> hierarchical scan -> scatter (srcs + bf16 EA perm)
// ---------------------------------------------------------------------------
__global__ __launch_bounds__(256) void hist_kernel(
    const int* __restrict__ EI, int* __restrict__ deg, int E)
{
    int e = blockIdx.x * 256 + threadIdx.x;
    if (e < E) atomicAdd(&deg[EI[E + e]], 1);
}

__global__ __launch_bounds__(1024) void scanA(
    const int* __restrict__ deg, int* __restrict__ rowptr,
    int* __restrict__ psums, int N)
{
    __shared__ int tmp[1024];
    const int t = threadIdx.x;
    const int i = blockIdx.x * 1024 + t;
    int v = (i < N) ? deg[i] : 0;
    tmp[t] = v;
    __syncthreads();
    for (int off = 1; off < 1024; off <<= 1) {
        int add = (t >= off) ? tmp[t - off] : 0;
        __syncthreads();
        tmp[t] += add;
        __syncthreads();
    }
    if (i < N) rowptr[i + 1] = tmp[t];
    if (t == 1023) psums[blockIdx.x] = tmp[1023];
}

__global__ __launch_bounds__(1024) void scanB(int* __restrict__ psums, int nb)
{
    __shared__ int tmp[1024];
    const int t = threadIdx.x;
    int v = (t < nb) ? psums[t] : 0;
    tmp[t] = v;
    __syncthreads();
    for (int off = 1; off < 1024; off <<= 1) {
        int add = (t >= off) ? tmp[t - off] : 0;
        __syncthreads();
        tmp[t] += add;
        __syncthreads();
    }
    if (t < nb) psums[t] = tmp[t] - v;   // exclusive
}

__global__ __launch_bounds__(256) void scanC(
    int* __restrict__ rowptr, int* __restrict__ cursor,
    const int* __restrict__ psums, int N)
{
    int i = blockIdx.x * 256 + threadIdx.x;
    if (i == 0) { rowptr[0] = 0; cursor[0] = 0; }
    if (i < N) {
        int val = rowptr[i + 1] + psums[i >> 10];
        rowptr[i + 1] = val;
        if (i + 1 < N) cursor[i + 1] = val;
    }
}

__global__ __launch_bounds__(256) void scatter_kernel(
    const int* __restrict__ EI, const float* __restrict__ EA,
    int* __restrict__ cursor, int* __restrict__ srcs,
    unsigned short* __restrict__ EAP, int E)
{
    int e = blockIdx.x * 256 + threadIdx.x;
    if (e >= E) return;
    int dst = EI[E + e];
    int pos = atomicAdd(&cursor[dst], 1);
    srcs[pos] = EI[e];
    const float4* s4 = (const float4*)(EA + (size_t)e * EDIM);
    unsigned short* op = EAP + (size_t)pos * EDIM;
#pragma unroll
    for (int j = 0; j < 4; ++j) {
        float4 a = s4[2 * j], b = s4[2 * j + 1];
        ushort8 u;
        u[0] = f2bf(a.x); u[1] = f2bf(a.y); u[2] = f2bf(a.z); u[3] = f2bf(a.w);
        u[4] = f2bf(b.x); u[5] = f2bf(b.y); u[6] = f2bf(b.z); u[7] = f2bf(b.w);
        *(ushort8*)(op + j * 8) = u;
    }
}

// ---------------------------------------------------------------------------
// gather: 1 wave per node; 4 edge groups x 16 lanes (lane owns 8 dims).
// alpha reduce = 2 DPP ops within the head's aligned quad.
// Writes (in place into SB): preout = sum(ex*v)/den + skip
// and SAS (bf16) = sum(ex*ea)/den  -> corr GEMM later.
// ---------------------------------------------------------------------------
__global__ __launch_bounds__(256) void gather_pass(
    const int* __restrict__ rowptr, const int* __restrict__ srcs,
    const unsigned short* __restrict__ EAP,
    const unsigned short* __restrict__ Q, const unsigned short* __restrict__ K,
    const unsigned short* __restrict__ V, const float* __restrict__ QE,
    float* __restrict__ SB, unsigned short* __restrict__ SAS, int N)
{
    const int lane = threadIdx.x & 63;
    const int wid = threadIdx.x >> 6;
    const int n = blockIdx.x * 4 + wid;
    if (n >= N) return;
    const int g = lane & 15;        // dim slice: d = g*8..+8 (head g/4)
    const int grp = lane >> 4;      // edge group 0..3

    float q8[8], qe8[8];
    {
        bf16x8 qb = *(const bf16x8*)(Q + (size_t)n * D + g * 8);
#pragma unroll
        for (int j = 0; j < 8; ++j) q8[j] = bf2f((unsigned short)qb[j]);
        float4 a = *(const float4*)(QE + (size_t)n * D + g * 8);
        float4 b = *(const float4*)(QE + (size_t)n * D + g * 8 + 4);
        qe8[0] = a.x; qe8[1] = a.y; qe8[2] = a.z; qe8[3] = a.w;
        qe8[4] = b.x; qe8[5] = b.y; qe8[6] = b.z; qe8[7] = b.w;
    }

    float acc[8], sa[8], den = 0.f;
#pragma unroll
    for (int j = 0; j < 8; ++j) { acc[j] = 0.f; sa[j] = 0.f; }

    const int i0 = rowptr[n], i1 = rowptr[n + 1];

    int idx = i0 + grp;
    int src_c = (idx < i1) ? srcs[idx] : -1;

    for (int base = i0; base < i1; base += 4, idx += 4) {
        const int src = src_c;
        {
            int idx_n = idx + 4;
            src_c = (idx_n < i1) ? srcs[idx_n] : -1;
        }
        bf16x8 kb = {0,0,0,0,0,0,0,0};
        bf16x8 vb = {0,0,0,0,0,0,0,0};
        bf16x8 eb = {0,0,0,0,0,0,0,0};
        if (src >= 0) {
            kb = *(const bf16x8*)(K + (size_t)src * D + g * 8);
            vb = *(const bf16x8*)(V + (size_t)src * D + g * 8);
            eb = *(const bf16x8*)(EAP + (size_t)idx * EDIM + (g & 3) * 8);
        }
        float ef[8], vf[8];
        float p = 0.f;
#pragma unroll
        for (int j = 0; j < 8; ++j) {
            float kf = bf2f((unsigned short)kb[j]);
            ef[j] = bf2f((unsigned short)eb[j]);
            vf[j] = bf2f((unsigned short)vb[j]);
            p = fmaf(q8[j], kf, fmaf(ef[j], qe8[j], p));
        }
        p = quad_add(p);                      // full 32-dim dot for this head
        float ex = (src >= 0) ? __expf(p * 0.17677669529663689f) : 0.f;
        den += ex;
#pragma unroll
        for (int j = 0; j < 8; ++j) {
            acc[j] = fmaf(ex, vf[j], acc[j]);
            sa[j]  = fmaf(ex, ef[j], sa[j]);
        }
    }

    // combine the 4 edge groups (once per node)
#pragma unroll
    for (int off = 16; off <= 32; off <<= 1) {
        den += __shfl_xor(den, off, 64);
#pragma unroll
        for (int j = 0; j < 8; ++j) {
            acc[j] += __shfl_xor(acc[j], off, 64);
            sa[j]  += __shfl_xor(sa[j],  off, 64);
        }
    }

    if (grp == 0) {
        const float rden = 1.f / (den + 1e-16f);
        float* so = SB + (size_t)n * D + g * 8;
        unsigned short* po = SAS + (size_t)n * D + g * 8;
#pragma unroll
        for (int j = 0; j < 8; ++j) {
            so[j] = fmaf(acc[j], rden, so[j]);    // + skip (in place)
            po[j] = f2bf(sa[j] * rden);
        }
    }
}

// ---------------------------------------------------------------------------
// combine_mlp1: OUT = preout + SAS @ WtCorr (MFMA, C-init = preout);
// then H1 = gelu(OUT @ W1 + b1) via LDS bounce. OUT written in place into SB.
// ---------------------------------------------------------------------------
__global__ __launch_bounds__(256) void combine_mlp1(
    float* __restrict__ SB, const unsigned short* __restrict__ SAS,
    const unsigned short* __restrict__ WtC, const unsigned short* __restrict__ Wt1,
    const float* __restrict__ b1, unsigned short* __restrict__ H1, int N)
{
    __shared__ float lds[64 * 132];
    const int lane = threadIdx.x & 63;
    const int w = threadIdx.x >> 6;
    const int row0 = blockIdx.x * 64 + w * 16;
    const int lrow = lane & 15;
    const int kb = (lane >> 4) * 8;
    const int rq = (lane >> 4) * 4;

    bf16x8 af[4];
    {
        int ar = row0 + lrow; if (ar > N - 1) ar = N - 1;
        const unsigned short* xr = SAS + (size_t)ar * D + kb;
#pragma unroll
        for (int kf = 0; kf < 4; ++kf) af[kf] = *(const bf16x8*)(xr + kf * 32);
    }
    f32x4 acc[8];
#pragma unroll
    for (int nf = 0; nf < 8; ++nf) {
        const int col = nf * 16 + lrow;
#pragma unroll
        for (int i = 0; i < 4; ++i) {
            int r = row0 + rq + i;
            acc[nf][i] = (r < N) ? SB[(size_t)r * D + col] : 0.f;
        }
    }
#pragma unroll
    for (int nf = 0; nf < 8; ++nf) {
        const unsigned short* wp = WtC + (size_t)(nf * 16 + lrow) * 128 + kb;
#pragma unroll
        for (int kf = 0; kf < 4; ++kf) {
            bf16x8 bfr = *(const bf16x8*)(wp + kf * 32);
            acc[nf] = __builtin_amdgcn_mfma_f32_16x16x32_bf16(af[kf], bfr, acc[nf], 0, 0, 0);
        }
    }
#pragma unroll
    for (int nf = 0; nf < 8; ++nf) {
        const int col = nf * 16 + lrow;
#pragma unroll
        for (int i = 0; i < 4; ++i) {
            int r = row0 + rq + i;
            lds[(w * 16 + rq + i) * 132 + col] = acc[nf][i];
            if (r < N) SB[(size_t)r * D + col] = acc[nf][i];   // OUT
        }
    }
    __syncthreads();
    bf16x8 af2[4];
#pragma unroll
    for (int kf = 0; kf < 4; ++kf) {
        const float* lr = &lds[(w * 16 + lrow) * 132 + kb + kf * 32];
#pragma unroll
        for (int j = 0; j < 8; ++j) af2[kf][j] = (short)f2bf(lr[j]);
    }
    f32x4 acc2[8];
#pragma unroll
    for (int nf = 0; nf < 8; ++nf) acc2[nf] = (f32x4){0.f, 0.f, 0.f, 0.f};
#pragma unroll
    for (int nf = 0; nf < 8; ++nf) {
        const unsigned short* wp = Wt1 + (size_t)(nf * 16 + lrow) * 128 + kb;
#pragma unroll
        for (int kf = 0; kf < 4; ++kf) {
            bf16x8 bfr = *(const bf16x8*)(wp + kf * 32);
            acc2[nf] = __builtin_amdgcn_mfma_f32_16x16x32_bf16(af2[kf], bfr, acc2[nf], 0, 0, 0);
        }
    }
#pragma unroll
    for (int nf = 0; nf < 8; ++nf) {
        const int col = nf * 16 + lrow;
        const float bb = b1[col];
#pragma unroll
        for (int i = 0; i < 4; ++i) {
            int r = row0 + rq + i;
            if (r < N) H1[(size_t)r * D + col] = f2bf(gelu_fast(acc2[nf][i] + bb));
        }
    }
}

// ---------------------------------------------------------------------------
// mlp2: FINAL = OUT + gelu(H1 @ W2 + b2)
// ---------------------------------------------------------------------------
__global__ __launch_bounds__(256) void mlp2_kernel(
    const unsigned short* __restrict__ H1, const float* __restrict__ OUT,
    const unsigned short* __restrict__ Wt2, const float* __restrict__ b2,
    float* __restrict__ FINAL, int N)
{
    const int lane = threadIdx.x & 63;
    const int w = threadIdx.x >> 6;
    const int row0 = blockIdx.x * 64 + w * 16;
    const int lrow = lane & 15;
    const int kb = (lane >> 4) * 8;
    const int rq = (lane >> 4) * 4;

    bf16x8 af[4];
    {
        int ar = row0 + lrow; if (ar > N - 1) ar = N - 1;
        const unsigned short* xr = H1 + (size_t)ar * D + kb;
#pragma unroll
        for (int kf = 0; kf < 4; ++kf) af[kf] = *(const bf16x8*)(xr + kf * 32);
    }
    f32x4 acc[8];
#pragma unroll
    for (int nf = 0; nf < 8; ++nf) acc[nf] = (f32x4){0.f, 0.f, 0.f, 0.f};
#pragma unroll
    for (int nf = 0; nf < 8; ++nf) {
        const unsigned short* wp = Wt2 + (size_t)(nf * 16 + lrow) * 128 + kb;
#pragma unroll
        for (int kf = 0; kf < 4; ++kf) {
            bf16x8 bfr = *(const bf16x8*)(wp + kf * 32);
            acc[nf] = __builtin_amdgcn_mfma_f32_16x16x32_bf16(af[kf], bfr, acc[nf], 0, 0, 0);
        }
    }
#pragma unroll
    for (int nf = 0; nf < 8; ++nf) {
        const int col = nf * 16 + lrow;
        const float bb = b2[col];
#pragma unroll
        for (int i = 0; i < 4; ++i) {
            int r = row0 + rq + i;
            if (r < N) {
                size_t o = (size_t)r * D + col;
                FINAL[o] = OUT[o] + gelu_fast(acc[nf][i] + bb);
            }
        }
    }
}

// ---------------------------------------------------------------------------
extern "C" void kernel_launch(void* const* d_in, const int* in_sizes, int n_in,
                              void* d_out, int out_size, void* d_ws, size_t ws_size,
                              hipStream_t stream)
{
    const float* x   = (const float*)d_in[0];
    const int*   EI  = (const int*)  d_in[1];
    const float* EA  = (const float*)d_in[2];
    const float* Wq  = (const float*)d_in[3];
    const float* bq  = (const float*)d_in[4];
    const float* Wk  = (const float*)d_in[5];
    const float* bk  = (const float*)d_in[6];
    const float* Wv  = (const float*)d_in[7];
    const float* bv  = (const float*)d_in[8];
    const float* We  = (const float*)d_in[9];
    const float* Wsk = (const float*)d_in[10];
    const float* bsk = (const float*)d_in[11];
    const float* W1  = (const float*)d_in[12];
    const float* b1  = (const float*)d_in[13];
    const float* W2  = (const float*)d_in[14];
    const float* b2  = (const float*)d_in[15];

    const int N = in_sizes[0] / D;
    const int E = in_sizes[1] / 2;

    char* p = (char*)d_ws;
    auto alloc = [&](size_t bytes) -> void* {
        void* r = (void*)p;
        p += (bytes + 255) & ~(size_t)255;
        return r;
    };
    float*          Sb     = (float*)         alloc((size_t)N * D * 4); // skip->preout->OUT
    float*          QEb    = (float*)         alloc((size_t)N * D * 4); // QE; later H1 (bf16)
    unsigned short* Qb     = (unsigned short*)alloc((size_t)N * D * 2);
    unsigned short* Kb     = (unsigned short*)alloc((size_t)N * D * 2);
    unsigned short* Vb     = (unsigned short*)alloc((size_t)N * D * 2);
    unsigned short* SASb   = (unsigned short*)alloc((size_t)N * D * 2);
    unsigned short* EAPb   = (unsigned short*)alloc((size_t)E * EDIM * 2);
    int*            srcsb  = (int*)           alloc((size_t)E * 4);
    unsigned short* Wt     = (unsigned short*)alloc((size_t)8 * 16384 * 2);
    float*          bqEb   = (float*)         alloc((size_t)128 * 4);
    int*            deg    = (int*)           alloc((size_t)N * 4);
    int*            rowptr = (int*)           alloc((size_t)(N + 1) * 4);
    int*            cursor = (int*)           alloc((size_t)(N + 1) * 4);
    int*            psums  = (int*)           alloc((size_t)1024 * 4);

    unsigned short* H1b = (unsigned short*)QEb;   // alias: QE dead after gather

    hipMemsetAsync(deg, 0, (size_t)N * sizeof(int), stream);

    const int NB = (N + 63) / 64;
    const int EB = (E + 255) / 256;
    const int SB_ = (N + 1023) / 1024;

    prep_bqe<<<1, 128, 0, stream>>>(bq, We, bqEb);
    prep_wt<<<(8 * 16384) / 256, 256, 0, stream>>>(Wq, Wk, Wv, Wsk, W1, W2,
                                                   We, Wt);

    gemm_qkvs<<<NB, 256, 0, stream>>>(x, Wt, bq, bk, bv, bsk, bqEb,
                                      Qb, Kb, Vb, Sb, QEb, N);

    hist_kernel<<<EB, 256, 0, stream>>>(EI, deg, E);
    scanA<<<SB_, 1024, 0, stream>>>(deg, rowptr, psums, N);
    scanB<<<1, 1024, 0, stream>>>(psums, SB_);
    scanC<<<(N + 255) / 256, 256, 0, stream>>>(rowptr, cursor, psums, N);
    scatter_kernel<<<EB, 256, 0, stream>>>(EI, EA, cursor, srcsb, EAPb, E);

    gather_pass<<<(N + 3) / 4, 256, 0, stream>>>(
        rowptr, srcsb, EAPb, Qb, Kb, Vb, QEb, Sb, SASb, N);

    combine_mlp1<<<NB, 256, 0, stream>>>(Sb, SASb, Wt + (size_t)7 * 16384,
                                         Wt + (size_t)4 * 16384, b1, H1b, N);
    mlp2_kernel<<<NB, 256, 0, stream>>>(H1b, Sb, Wt + (size_t)5 * 16384, b2,
                                        (float*)d_out, N);
}

// Round 6
// 305.782 us; speedup vs baseline: 3.3013x; 1.2165x over previous
//
#include <hip/hip_runtime.h>
#include <math.h>

// ---------------------------------------------------------------------------
// GraphTransformerBlock: TransformerConv (4 heads x 32) + residual MLP.
// Round 6: GEMM-family de-stall. Weight tables pre-swizzled (kk ^= (col&7)<<3,
// 16B-granular involution); every GEMM kernel stages its 32KB weight tile
// into LDS (conflict-free ds_read_b128 B-frags) instead of chaining 160
// global L2 loads per wave. gemm_qkvs split by matrix (blockIdx.y) for
// occupancy (5 blocks/CU). combine_mlp1 bounce -> bf16, sequential re-stage.
// ---------------------------------------------------------------------------

#define D 128
#define EDIM 32

using bf16x8 = __attribute__((ext_vector_type(8))) short;
using f32x4  = __attribute__((ext_vector_type(4))) float;
using ushort8 = __attribute__((ext_vector_type(8))) unsigned short;

__device__ inline unsigned short f2bf(float f) {
    unsigned int u = __float_as_uint(f);
    u += 0x7FFFu + ((u >> 16) & 1u);          // round-to-nearest-even
    return (unsigned short)(u >> 16);
}
__device__ inline float bf2f(unsigned short h) {
    return __uint_as_float(((unsigned int)h) << 16);
}
__device__ inline float gelu_fast(float x) {
    float x3 = x * x * x;
    float u = 0.7978845608028654f * (x + 0.044715f * x3);
    float t = 1.f - 2.f / (__expf(2.f * u) + 1.f);   // tanh(u)
    return 0.5f * x * (1.f + t);
}
// sum over aligned 4-lane quad via DPP quad_perm (all 4 lanes get the sum)
__device__ inline float quad_add(float x) {
    int a = __builtin_amdgcn_update_dpp(0, __float_as_int(x), 0xB1, 0xF, 0xF, true);
    x += __int_as_float(a);
    a = __builtin_amdgcn_update_dpp(0, __float_as_int(x), 0x4E, 0xF, 0xF, true);
    x += __int_as_float(a);
    return x;
}

// swizzled B-frag read: element (col, kk0..kk0+7) of the staged weight tile
__device__ inline bf16x8 ldsB(const unsigned short* sw, int col, int kk0) {
    return *(const bf16x8*)(sw + col * 128 + (kk0 ^ ((col & 7) << 3)));
}

// ---------------------------------------------------------------------------
// prep_bqe: bqE[j] = sum_c bq[h*32+c] * We[k][h*32+c],  j = h*32+k
// ---------------------------------------------------------------------------
__global__ __launch_bounds__(128) void prep_bqe(
    const float* __restrict__ bq, const float* __restrict__ We,
    float* __restrict__ bqE)
{
    const int j = threadIdx.x;
    const int hb = j & 96, k = j & 31;
    const float* wek = We + (size_t)k * D + hb;
    float s = 0.f;
#pragma unroll 8
    for (int c = 0; c < 32; ++c) s = fmaf(bq[hb + c], wek[c], s);
    bqE[j] = s;
}

// ---------------------------------------------------------------------------
// prep_wt: 8 bf16 weight tables, MFMA-B layout, PRE-SWIZZLED:
//   Wt[m][col*128 + (kk ^ ((col&7)<<3))] = W_m[kk][col]
//   m: 0=Wq 1=Wk 2=Wv 3=Wskip 4=W1 5=W2 6=WqE (inline dot) 7=WtCorr
// ---------------------------------------------------------------------------
__global__ __launch_bounds__(256) void prep_wt(
    const float* __restrict__ Wq, const float* __restrict__ Wk,
    const float* __restrict__ Wv, const float* __restrict__ Wsk,
    const float* __restrict__ W1, const float* __restrict__ W2,
    const float* __restrict__ We, unsigned short* __restrict__ Wt)
{
    int t = blockIdx.x * 256 + threadIdx.x;
    int m = t >> 14;
    int r = t & 16383;
    int col = r & 127, kk = r >> 7;
    float v;
    if (m < 6) {
        const float* W = (m == 0) ? Wq : (m == 1) ? Wk : (m == 2) ? Wv
                       : (m == 3) ? Wsk : (m == 4) ? W1 : W2;
        v = W[(size_t)kk * D + col];
    } else if (m == 6) {
        // WqE[kk][col] = sum_c Wq[kk][hb+c] * We[col&31][hb+c], hb=(col>>5)*32
        const int hb = col & 96;
        const float* wqr = Wq + (size_t)kk * D + hb;
        const float* wer = We + (size_t)(col & 31) * D + hb;
        float s = 0.f;
#pragma unroll 8
        for (int c = 0; c < 32; ++c) s = fmaf(wqr[c], wer[c], s);
        v = s;
    } else {
        // corr GEMM B: B[j=h*32+k][d=h*32+c] = We[k][d] if same head else 0
        v = ((kk >> 5) == (col >> 5)) ? We[(size_t)(kk & 31) * D + col] : 0.f;
    }
    Wt[(size_t)m * 16384 + (size_t)col * 128 + (kk ^ ((col & 7) << 3))] = f2bf(v);
}

// ---------------------------------------------------------------------------
// gemm_qkvs: blockIdx.y = m (0:Q 1:K 2:V 3:skip 4:QE). 64 rows/block.
// Weight tile staged to LDS; B-frags via conflict-free swizzled ds_read_b128.
// ---------------------------------------------------------------------------
__global__ __launch_bounds__(256) void gemm_qkvs(
    const float* __restrict__ x, const unsigned short* __restrict__ Wt,
    const float* __restrict__ bq, const float* __restrict__ bk,
    const float* __restrict__ bv, const float* __restrict__ bs,
    const float* __restrict__ bqE,
    unsigned short* __restrict__ Q, unsigned short* __restrict__ K,
    unsigned short* __restrict__ V, float* __restrict__ S,
    float* __restrict__ QE, int N)
{
    __shared__ unsigned short sw[16384];
    const int m = blockIdx.y;
    const int widx = (m < 4) ? m : 6;
    const int t = threadIdx.x;
    const int lane = t & 63;
    const int w = t >> 6;
    const int row0 = blockIdx.x * 64 + w * 16;
    const int lrow = lane & 15;
    const int kb = (lane >> 4) * 8;
    const int rq = (lane >> 4) * 4;

    // issue weight-staging loads first (latency overlaps A-frag work)
    const unsigned short* gsrc = Wt + (size_t)widx * 16384;
    ushort8 stg[8];
#pragma unroll
    for (int it = 0; it < 8; ++it)
        stg[it] = *(const ushort8*)(gsrc + (t + it * 256) * 8);

    bf16x8 af[4];
    {
        int ar = row0 + lrow; if (ar > N - 1) ar = N - 1;
        const float* xr = x + (size_t)ar * D + kb;
#pragma unroll
        for (int kf = 0; kf < 4; ++kf) {
            float4 p0 = *(const float4*)(xr + kf * 32);
            float4 p1 = *(const float4*)(xr + kf * 32 + 4);
            bf16x8 a;
            a[0] = (short)f2bf(p0.x); a[1] = (short)f2bf(p0.y);
            a[2] = (short)f2bf(p0.z); a[3] = (short)f2bf(p0.w);
            a[4] = (short)f2bf(p1.x); a[5] = (short)f2bf(p1.y);
            a[6] = (short)f2bf(p1.z); a[7] = (short)f2bf(p1.w);
            af[kf] = a;
        }
    }

#pragma unroll
    for (int it = 0; it < 8; ++it)
        *(ushort8*)(&sw[(t + it * 256) * 8]) = stg[it];
    __syncthreads();

    const float* bias = (m == 0) ? bq : (m == 1) ? bk : (m == 2) ? bv
                      : (m == 3) ? bs : bqE;
    f32x4 acc[8];
#pragma unroll
    for (int nf = 0; nf < 8; ++nf) acc[nf] = (f32x4){0.f, 0.f, 0.f, 0.f};
#pragma unroll
    for (int nf = 0; nf < 8; ++nf) {
        const int col = nf * 16 + lrow;
#pragma unroll
        for (int kf = 0; kf < 4; ++kf)
            acc[nf] = __builtin_amdgcn_mfma_f32_16x16x32_bf16(
                af[kf], ldsB(sw, col, kf * 32 + kb), acc[nf], 0, 0, 0);
    }
#pragma unroll
    for (int nf = 0; nf < 8; ++nf) {
        const int col = nf * 16 + lrow;
        const float bb = bias[col];
#pragma unroll
        for (int i = 0; i < 4; ++i) {
            int r = row0 + rq + i;
            if (r < N) {
                float v = acc[nf][i] + bb;
                size_t o = (size_t)r * D + col;
                if (m == 0) Q[o] = f2bf(v);
                else if (m == 1) K[o] = f2bf(v);
                else if (m == 2) V[o] = f2bf(v);
                else if (m == 3) S[o] = v;
                else QE[o] = v;
            }
        }
    }
}

// ---------------------------------------------------------------------------
// CSR construction: hist -> hierarchical scan -> scatter (srcs + bf16 EA perm)
// ---------------------------------------------------------------------------
__global__ __launch_bounds__(256) void hist_kernel(
    const int* __restrict__ EI, int* __restrict__ deg, int E)
{
    int e = blockIdx.x * 256 + threadIdx.x;
    if (e < E) atomicAdd(&deg[EI[E + e]], 1);
}

__global__ __launch_bounds__(1024) void scanA(
    const int* __restrict__ deg, int* __restrict__ rowptr,
    int* __restrict__ psums, int N)
{
    __shared__ int tmp[1024];
    const int t = threadIdx.x;
    const int i = blockIdx.x * 1024 + t;
    int v = (i < N) ? deg[i] : 0;
    tmp[t] = v;
    __syncthreads();
    for (int off = 1; off < 1024; off <<= 1) {
        int add = (t >= off) ? tmp[t - off] : 0;
        __syncthreads();
        tmp[t] += add;
        __syncthreads();
    }
    if (i < N) rowptr[i + 1] = tmp[t];
    if (t == 1023) psums[blockIdx.x] = tmp[1023];
}

__global__ __launch_bounds__(1024) void scanB(int* __restrict__ psums, int nb)
{
    __shared__ int tmp[1024];
    const int t = threadIdx.x;
    int v = (t < nb) ? psums[t] : 0;
    tmp[t] = v;
    __syncthreads();
    for (int off = 1; off < 1024; off <<= 1) {
        int add = (t >= off) ? tmp[t - off] : 0;
        __syncthreads();
        tmp[t] += add;
        __syncthreads();
    }
    if (t < nb) psums[t] = tmp[t] - v;   // exclusive
}

__global__ __launch_bounds__(256) void scanC(
    int* __restrict__ rowptr, int* __restrict__ cursor,
    const int* __restrict__ psums, int N)
{
    int i = blockIdx.x * 256 + threadIdx.x;
    if (i == 0) { rowptr[0] = 0; cursor[0] = 0; }
    if (i < N) {
        int val = rowptr[i + 1] + psums[i >> 10];
        rowptr[i + 1] = val;
        if (i + 1 < N) cursor[i + 1] = val;
    }
}

__global__ __launch_bounds__(256) void scatter_kernel(
    const int* __restrict__ EI, const float* __restrict__ EA,
    int* __restrict__ cursor, int* __restrict__ srcs,
    unsigned short* __restrict__ EAP, int E)
{
    int e = blockIdx.x * 256 + threadIdx.x;
    if (e >= E) return;
    int dst = EI[E + e];
    int pos = atomicAdd(&cursor[dst], 1);
    srcs[pos] = EI[e];
    const float4* s4 = (const float4*)(EA + (size_t)e * EDIM);
    unsigned short* op = EAP + (size_t)pos * EDIM;
#pragma unroll
    for (int j = 0; j < 4; ++j) {
        float4 a = s4[2 * j], b = s4[2 * j + 1];
        ushort8 u;
        u[0] = f2bf(a.x); u[1] = f2bf(a.y); u[2] = f2bf(a.z); u[3] = f2bf(a.w);
        u[4] = f2bf(b.x); u[5] = f2bf(b.y); u[6] = f2bf(b.z); u[7] = f2bf(b.w);
        *(ushort8*)(op + j * 8) = u;
    }
}

// ---------------------------------------------------------------------------
// gather: 1 wave per node; 4 edge groups x 16 lanes (lane owns 8 dims).
// alpha reduce = 2 DPP ops within the head's aligned quad.
// Writes (in place into SB): preout = sum(ex*v)/den + skip
// and SAS (bf16) = sum(ex*ea)/den  -> corr GEMM later.
// ---------------------------------------------------------------------------
__global__ __launch_bounds__(256) void gather_pass(
    const int* __restrict__ rowptr, const int* __restrict__ srcs,
    const unsigned short* __restrict__ EAP,
    const unsigned short* __restrict__ Q, const unsigned short* __restrict__ K,
    const unsigned short* __restrict__ V, const float* __restrict__ QE,
    float* __restrict__ SB, unsigned short* __restrict__ SAS, int N)
{
    const int lane = threadIdx.x & 63;
    const int wid = threadIdx.x >> 6;
    const int n = blockIdx.x * 4 + wid;
    if (n >= N) return;
    const int g = lane & 15;        // dim slice: d = g*8..+8 (head g/4)
    const int grp = lane >> 4;      // edge group 0..3

    float q8[8], qe8[8];
    {
        bf16x8 qb = *(const bf16x8*)(Q + (size_t)n * D + g * 8);
#pragma unroll
        for (int j = 0; j < 8; ++j) q8[j] = bf2f((unsigned short)qb[j]);
        float4 a = *(const float4*)(QE + (size_t)n * D + g * 8);
        float4 b = *(const float4*)(QE + (size_t)n * D + g * 8 + 4);
        qe8[0] = a.x; qe8[1] = a.y; qe8[2] = a.z; qe8[3] = a.w;
        qe8[4] = b.x; qe8[5] = b.y; qe8[6] = b.z; qe8[7] = b.w;
    }

    float acc[8], sa[8], den = 0.f;
#pragma unroll
    for (int j = 0; j < 8; ++j) { acc[j] = 0.f; sa[j] = 0.f; }

    const int i0 = rowptr[n], i1 = rowptr[n + 1];

    int idx = i0 + grp;
    int src_c = (idx < i1) ? srcs[idx] : -1;

    for (int base = i0; base < i1; base += 4, idx += 4) {
        const int src = src_c;
        {
            int idx_n = idx + 4;
            src_c = (idx_n < i1) ? srcs[idx_n] : -1;
        }
        bf16x8 kb = {0,0,0,0,0,0,0,0};
        bf16x8 vb = {0,0,0,0,0,0,0,0};
        bf16x8 eb = {0,0,0,0,0,0,0,0};
        if (src >= 0) {
            kb = *(const bf16x8*)(K + (size_t)src * D + g * 8);
            vb = *(const bf16x8*)(V + (size_t)src * D + g * 8);
            eb = *(const bf16x8*)(EAP + (size_t)idx * EDIM + (g & 3) * 8);
        }
        float ef[8], vf[8];
        float p = 0.f;
#pragma unroll
        for (int j = 0; j < 8; ++j) {
            float kf = bf2f((unsigned short)kb[j]);
            ef[j] = bf2f((unsigned short)eb[j]);
            vf[j] = bf2f((unsigned short)vb[j]);
            p = fmaf(q8[j], kf, fmaf(ef[j], qe8[j], p));
        }
        p = quad_add(p);                      // full 32-dim dot for this head
        float ex = (src >= 0) ? __expf(p * 0.17677669529663689f) : 0.f;
        den += ex;
#pragma unroll
        for (int j = 0; j < 8; ++j) {
            acc[j] = fmaf(ex, vf[j], acc[j]);
            sa[j]  = fmaf(ex, ef[j], sa[j]);
        }
    }

    // combine the 4 edge groups (once per node)
#pragma unroll
    for (int off = 16; off <= 32; off <<= 1) {
        den += __shfl_xor(den, off, 64);
#pragma unroll
        for (int j = 0; j < 8; ++j) {
            acc[j] += __shfl_xor(acc[j], off, 64);
            sa[j]  += __shfl_xor(sa[j],  off, 64);
        }
    }

    if (grp == 0) {
        const float rden = 1.f / (den + 1e-16f);
        float* so = SB + (size_t)n * D + g * 8;
        unsigned short* po = SAS + (size_t)n * D + g * 8;
#pragma unroll
        for (int j = 0; j < 8; ++j) {
            so[j] = fmaf(acc[j], rden, so[j]);    // + skip (in place)
            po[j] = f2bf(sa[j] * rden);
        }
    }
}

// ---------------------------------------------------------------------------
// combine_mlp1: OUT = preout + SAS @ WtCorr (C-init = preout from SB);
// H1 = gelu(OUT @ W1 + b1). Weights staged sequentially in one 32KB LDS
// buffer; OUT bounced through bf16 LDS (pad 136). OUT persists into SB.
// ---------------------------------------------------------------------------
__global__ __launch_bounds__(256) void combine_mlp1(
    float* __restrict__ SB, const unsigned short* __restrict__ SAS,
    const unsigned short* __restrict__ WtC, const unsigned short* __restrict__ Wt1,
    const float* __restrict__ b1, unsigned short* __restrict__ H1, int N)
{
    __shared__ unsigned short sw[16384];
    __shared__ unsigned short bounce[64 * 136];
    const int t = threadIdx.x;
    const int lane = t & 63;
    const int w = t >> 6;
    const int row0 = blockIdx.x * 64 + w * 16;
    const int lrow = lane & 15;
    const int kb = (lane >> 4) * 8;
    const int rq = (lane >> 4) * 4;

    // stage WtC (loads first; A-frags + C-init overlap the latency)
    ushort8 stg[8];
#pragma unroll
    for (int it = 0; it < 8; ++it)
        stg[it] = *(const ushort8*)(WtC + (t + it * 256) * 8);

    bf16x8 af[4];
    {
        int ar = row0 + lrow; if (ar > N - 1) ar = N - 1;
        const unsigned short* xr = SAS + (size_t)ar * D + kb;
#pragma unroll
        for (int kf = 0; kf < 4; ++kf) af[kf] = *(const bf16x8*)(xr + kf * 32);
    }
    f32x4 acc[8];
#pragma unroll
    for (int nf = 0; nf < 8; ++nf) {
        const int col = nf * 16 + lrow;
#pragma unroll
        for (int i = 0; i < 4; ++i) {
            int r = row0 + rq + i;
            acc[nf][i] = (r < N) ? SB[(size_t)r * D + col] : 0.f;
        }
    }

#pragma unroll
    for (int it = 0; it < 8; ++it)
        *(ushort8*)(&sw[(t + it * 256) * 8]) = stg[it];
    __syncthreads();

    // GEMM1: OUT = preout + SAS @ WtCorr
#pragma unroll
    for (int nf = 0; nf < 8; ++nf) {
        const int col = nf * 16 + lrow;
#pragma unroll
        for (int kf = 0; kf < 4; ++kf)
            acc[nf] = __builtin_amdgcn_mfma_f32_16x16x32_bf16(
                af[kf], ldsB(sw, col, kf * 32 + kb), acc[nf], 0, 0, 0);
    }
    __syncthreads();   // all GEMM1 LDS reads done before re-stage

    // stage Wt1 + write OUT (global + bf16 bounce)
#pragma unroll
    for (int it = 0; it < 8; ++it)
        stg[it] = *(const ushort8*)(Wt1 + (t + it * 256) * 8);
#pragma unroll
    for (int nf = 0; nf < 8; ++nf) {
        const int col = nf * 16 + lrow;
#pragma unroll
        for (int i = 0; i < 4; ++i) {
            int r = row0 + rq + i;
            float v = acc[nf][i];
            bounce[(w * 16 + rq + i) * 136 + col] = f2bf(v);
            if (r < N) SB[(size_t)r * D + col] = v;   // OUT
        }
    }
#pragma unroll
    for (int it = 0; it < 8; ++it)
        *(ushort8*)(&sw[(t + it * 256) * 8]) = stg[it];
    __syncthreads();

    // GEMM2: H1 = gelu(OUT @ W1 + b1)
    bf16x8 af2[4];
#pragma unroll
    for (int kf = 0; kf < 4; ++kf)
        af2[kf] = *(const bf16x8*)(&bounce[(w * 16 + lrow) * 136 + kb + kf * 32]);
    f32x4 acc2[8];
#pragma unroll
    for (int nf = 0; nf < 8; ++nf) acc2[nf] = (f32x4){0.f, 0.f, 0.f, 0.f};
#pragma unroll
    for (int nf = 0; nf < 8; ++nf) {
        const int col = nf * 16 + lrow;
#pragma unroll
        for (int kf = 0; kf < 4; ++kf)
            acc2[nf] = __builtin_amdgcn_mfma_f32_16x16x32_bf16(
                af2[kf], ldsB(sw, col, kf * 32 + kb), acc2[nf], 0, 0, 0);
    }
#pragma unroll
    for (int nf = 0; nf < 8; ++nf) {
        const int col = nf * 16 + lrow;
        const float bb = b1[col];
#pragma unroll
        for (int i = 0; i < 4; ++i) {
            int r = row0 + rq + i;
            if (r < N) H1[(size_t)r * D + col] = f2bf(gelu_fast(acc2[nf][i] + bb));
        }
    }
}

// ---------------------------------------------------------------------------
// mlp2: FINAL = OUT + gelu(H1 @ W2 + b2). Wt2 staged to LDS.
// ---------------------------------------------------------------------------
__global__ __launch_bounds__(256) void mlp2_kernel(
    const unsigned short* __restrict__ H1, const float* __restrict__ OUT,
    const unsigned short* __restrict__ Wt2, const float* __restrict__ b2,
    float* __restrict__ FINAL, int N)
{
    __shared__ unsigned short sw[16384];
    const int t = threadIdx.x;
    const int lane = t & 63;
    const int w = t >> 6;
    const int row0 = blockIdx.x * 64 + w * 16;
    const int lrow = lane & 15;
    const int kb = (lane >> 4) * 8;
    const int rq = (lane >> 4) * 4;

    ushort8 stg[8];
#pragma unroll
    for (int it = 0; it < 8; ++it)
        stg[it] = *(const ushort8*)(Wt2 + (t + it * 256) * 8);

    bf16x8 af[4];
    {
        int ar = row0 + lrow; if (ar > N - 1) ar = N - 1;
        const unsigned short* xr = H1 + (size_t)ar * D + kb;
#pragma unroll
        for (int kf = 0; kf < 4; ++kf) af[kf] = *(const bf16x8*)(xr + kf * 32);
    }

#pragma unroll
    for (int it = 0; it < 8; ++it)
        *(ushort8*)(&sw[(t + it * 256) * 8]) = stg[it];
    __syncthreads();

    f32x4 acc[8];
#pragma unroll
    for (int nf = 0; nf < 8; ++nf) acc[nf] = (f32x4){0.f, 0.f, 0.f, 0.f};
#pragma unroll
    for (int nf = 0; nf < 8; ++nf) {
        const int col = nf * 16 + lrow;
#pragma unroll
        for (int kf = 0; kf < 4; ++kf)
            acc[nf] = __builtin_amdgcn_mfma_f32_16x16x32_bf16(
                af[kf], ldsB(sw, col, kf * 32 + kb), acc[nf], 0, 0, 0);
    }
#pragma unroll
    for (int nf = 0; nf < 8; ++nf) {
        const int col = nf * 16 + lrow;
        const float bb = b2[col];
#pragma unroll
        for (int i = 0; i < 4; ++i) {
            int r = row0 + rq + i;
            if (r < N) {
                size_t o = (size_t)r * D + col;
                FINAL[o] = OUT[o] + gelu_fast(acc[nf][i] + bb);
            }
        }
    }
}

// ---------------------------------------------------------------------------
extern "C" void kernel_launch(void* const* d_in, const int* in_sizes, int n_in,
                              void* d_out, int out_size, void* d_ws, size_t ws_size,
                              hipStream_t stream)
{
    const float* x   = (const float*)d_in[0];
    const int*   EI  = (const int*)  d_in[1];
    const float* EA  = (const float*)d_in[2];
    const float* Wq  = (const float*)d_in[3];
    const float* bq  = (const float*)d_in[4];
    const float* Wk  = (const float*)d_in[5];
    const float* bk  = (const float*)d_in[6];
    const float* Wv  = (const float*)d_in[7];
    const float* bv  = (const float*)d_in[8];
    const float* We  = (const float*)d_in[9];
    const float* Wsk = (const float*)d_in[10];
    const float* bsk = (const float*)d_in[11];
    const float* W1  = (const float*)d_in[12];
    const float* b1  = (const float*)d_in[13];
    const float* W2  = (const float*)d_in[14];
    const float* b2  = (const float*)d_in[15];

    const int N = in_sizes[0] / D;
    const int E = in_sizes[1] / 2;

    char* p = (char*)d_ws;
    auto alloc = [&](size_t bytes) -> void* {
        void* r = (void*)p;
        p += (bytes + 255) & ~(size_t)255;
        return r;
    };
    float*          Sb     = (float*)         alloc((size_t)N * D * 4); // skip->preout->OUT
    float*          QEb    = (float*)         alloc((size_t)N * D * 4); // QE; later H1 (bf16)
    unsigned short* Qb     = (unsigned short*)alloc((size_t)N * D * 2);
    unsigned short* Kb     = (unsigned short*)alloc((size_t)N * D * 2);
    unsigned short* Vb     = (unsigned short*)alloc((size_t)N * D * 2);
    unsigned short* SASb   = (unsigned short*)alloc((size_t)N * D * 2);
    unsigned short* EAPb   = (unsigned short*)alloc((size_t)E * EDIM * 2);
    int*            srcsb  = (int*)           alloc((size_t)E * 4);
    unsigned short* Wt     = (unsigned short*)alloc((size_t)8 * 16384 * 2);
    float*          bqEb   = (float*)         alloc((size_t)128 * 4);
    int*            deg    = (int*)           alloc((size_t)N * 4);
    int*            rowptr = (int*)           alloc((size_t)(N + 1) * 4);
    int*            cursor = (int*)           alloc((size_t)(N + 1) * 4);
    int*            psums  = (int*)           alloc((size_t)1024 * 4);

    unsigned short* H1b = (unsigned short*)QEb;   // alias: QE dead after gather

    hipMemsetAsync(deg, 0, (size_t)N * sizeof(int), stream);

    const int NB = (N + 63) / 64;
    const int EB = (E + 255) / 256;
    const int SB_ = (N + 1023) / 1024;

    prep_bqe<<<1, 128, 0, stream>>>(bq, We, bqEb);
    prep_wt<<<(8 * 16384) / 256, 256, 0, stream>>>(Wq, Wk, Wv, Wsk, W1, W2,
                                                   We, Wt);

    gemm_qkvs<<<dim3(NB, 5), 256, 0, stream>>>(x, Wt, bq, bk, bv, bsk, bqEb,
                                               Qb, Kb, Vb, Sb, QEb, N);

    hist_kernel<<<EB, 256, 0, stream>>>(EI, deg, E);
    scanA<<<SB_, 1024, 0, stream>>>(deg, rowptr, psums, N);
    scanB<<<1, 1024, 0, stream>>>(psums, SB_);
    scanC<<<(N + 255) / 256, 256, 0, stream>>>(rowptr, cursor, psums, N);
    scatter_kernel<<<EB, 256, 0, stream>>>(EI, EA, cursor, srcsb, EAPb, E);

    gather_pass<<<(N + 3) / 4, 256, 0, stream>>>(
        rowptr, srcsb, EAPb, Qb, Kb, Vb, QEb, Sb, SASb, N);

    combine_mlp1<<<NB, 256, 0, stream>>>(Sb, SASb, Wt + (size_t)7 * 16384,
                                         Wt + (size_t)4 * 16384, b1, H1b, N);
    mlp2_kernel<<<NB, 256, 0, stream>>>(H1b, Sb, Wt + (size_t)5 * 16384, b2,
                                        (float*)d_out, N);
}

// Round 7
// 299.188 us; speedup vs baseline: 3.3740x; 1.0220x over previous
//
#include <hip/hip_runtime.h>
#include <math.h>

// ---------------------------------------------------------------------------
// GraphTransformerBlock: TransformerConv (4 heads x 32) + residual MLP.
// Round 7: gather de-stall. KV packed [K|V] per node (one 512B row/edge),
// Q/QE packed bf16 (QA), 2-edge unroll per 16-lane group (8 edges in
// flight/wave), srcs prefetched one iteration ahead. prep_bqe folded into
// prep_wt. GEMM family unchanged from round 6 (LDS-staged swizzled weights).
// ---------------------------------------------------------------------------

#define D 128
#define EDIM 32

using bf16x8 = __attribute__((ext_vector_type(8))) short;
using f32x4  = __attribute__((ext_vector_type(4))) float;
using ushort8 = __attribute__((ext_vector_type(8))) unsigned short;

__device__ inline unsigned short f2bf(float f) {
    unsigned int u = __float_as_uint(f);
    u += 0x7FFFu + ((u >> 16) & 1u);          // round-to-nearest-even
    return (unsigned short)(u >> 16);
}
__device__ inline float bf2f(unsigned short h) {
    return __uint_as_float(((unsigned int)h) << 16);
}
__device__ inline float gelu_fast(float x) {
    float x3 = x * x * x;
    float u = 0.7978845608028654f * (x + 0.044715f * x3);
    float t = 1.f - 2.f / (__expf(2.f * u) + 1.f);   // tanh(u)
    return 0.5f * x * (1.f + t);
}
// sum over aligned 4-lane quad via DPP quad_perm (all 4 lanes get the sum)
__device__ inline float quad_add(float x) {
    int a = __builtin_amdgcn_update_dpp(0, __float_as_int(x), 0xB1, 0xF, 0xF, true);
    x += __int_as_float(a);
    a = __builtin_amdgcn_update_dpp(0, __float_as_int(x), 0x4E, 0xF, 0xF, true);
    x += __int_as_float(a);
    return x;
}

// swizzled B-frag read: element (col, kk0..kk0+7) of the staged weight tile
__device__ inline bf16x8 ldsB(const unsigned short* sw, int col, int kk0) {
    return *(const bf16x8*)(sw + col * 128 + (kk0 ^ ((col & 7) << 3)));
}

// ---------------------------------------------------------------------------
// prep_wt: 8 bf16 weight tables, MFMA-B layout, PRE-SWIZZLED:
//   Wt[m][col*128 + (kk ^ ((col&7)<<3))] = W_m[kk][col]
//   m: 0=Wq 1=Wk 2=Wv 3=Wskip 4=W1 5=W2 6=WqE (inline dot) 7=WtCorr
// Extra block (blockIdx.x==512): bqE[j] = sum_c bq[hb+c]*We[k][hb+c]
// ---------------------------------------------------------------------------
__global__ __launch_bounds__(256) void prep_wt(
    const float* __restrict__ Wq, const float* __restrict__ Wk,
    const float* __restrict__ Wv, const float* __restrict__ Wsk,
    const float* __restrict__ W1, const float* __restrict__ W2,
    const float* __restrict__ We, const float* __restrict__ bq,
    unsigned short* __restrict__ Wt, float* __restrict__ bqE)
{
    int t = blockIdx.x * 256 + threadIdx.x;
    int m = t >> 14;
    int r = t & 16383;
    if (m >= 8) {                       // bqE tail block
        if (r < 128) {
            const int hb = r & 96, k = r & 31;
            const float* wek = We + (size_t)k * D + hb;
            float s = 0.f;
#pragma unroll 8
            for (int c = 0; c < 32; ++c) s = fmaf(bq[hb + c], wek[c], s);
            bqE[r] = s;
        }
        return;
    }
    int col = r & 127, kk = r >> 7;
    float v;
    if (m < 6) {
        const float* W = (m == 0) ? Wq : (m == 1) ? Wk : (m == 2) ? Wv
                       : (m == 3) ? Wsk : (m == 4) ? W1 : W2;
        v = W[(size_t)kk * D + col];
    } else if (m == 6) {
        // WqE[kk][col] = sum_c Wq[kk][hb+c] * We[col&31][hb+c], hb=(col>>5)*32
        const int hb = col & 96;
        const float* wqr = Wq + (size_t)kk * D + hb;
        const float* wer = We + (size_t)(col & 31) * D + hb;
        float s = 0.f;
#pragma unroll 8
        for (int c = 0; c < 32; ++c) s = fmaf(wqr[c], wer[c], s);
        v = s;
    } else {
        // corr GEMM B: B[j=h*32+k][d=h*32+c] = We[k][d] if same head else 0
        v = ((kk >> 5) == (col >> 5)) ? We[(size_t)(kk & 31) * D + col] : 0.f;
    }
    Wt[(size_t)m * 16384 + (size_t)col * 128 + (kk ^ ((col & 7) << 3))] = f2bf(v);
}

// ---------------------------------------------------------------------------
// gemm_qkvs: blockIdx.y = m (0:Q 1:K 2:V 3:skip 4:QE). 64 rows/block.
// Outputs packed: QA[n][256]=[Q|QE] bf16, KV[n][256]=[K|V] bf16, S f32.
// ---------------------------------------------------------------------------
__global__ __launch_bounds__(256) void gemm_qkvs(
    const float* __restrict__ x, const unsigned short* __restrict__ Wt,
    const float* __restrict__ bq, const float* __restrict__ bk,
    const float* __restrict__ bv, const float* __restrict__ bs,
    const float* __restrict__ bqE,
    unsigned short* __restrict__ QA, unsigned short* __restrict__ KV,
    float* __restrict__ S, int N)
{
    __shared__ unsigned short sw[16384];
    const int m = blockIdx.y;
    const int widx = (m < 4) ? m : 6;
    const int t = threadIdx.x;
    const int lane = t & 63;
    const int w = t >> 6;
    const int row0 = blockIdx.x * 64 + w * 16;
    const int lrow = lane & 15;
    const int kb = (lane >> 4) * 8;
    const int rq = (lane >> 4) * 4;

    // issue weight-staging loads first (latency overlaps A-frag work)
    const unsigned short* gsrc = Wt + (size_t)widx * 16384;
    ushort8 stg[8];
#pragma unroll
    for (int it = 0; it < 8; ++it)
        stg[it] = *(const ushort8*)(gsrc + (t + it * 256) * 8);

    bf16x8 af[4];
    {
        int ar = row0 + lrow; if (ar > N - 1) ar = N - 1;
        const float* xr = x + (size_t)ar * D + kb;
#pragma unroll
        for (int kf = 0; kf < 4; ++kf) {
            float4 p0 = *(const float4*)(xr + kf * 32);
            float4 p1 = *(const float4*)(xr + kf * 32 + 4);
            bf16x8 a;
            a[0] = (short)f2bf(p0.x); a[1] = (short)f2bf(p0.y);
            a[2] = (short)f2bf(p0.z); a[3] = (short)f2bf(p0.w);
            a[4] = (short)f2bf(p1.x); a[5] = (short)f2bf(p1.y);
            a[6] = (short)f2bf(p1.z); a[7] = (short)f2bf(p1.w);
            af[kf] = a;
        }
    }

#pragma unroll
    for (int it = 0; it < 8; ++it)
        *(ushort8*)(&sw[(t + it * 256) * 8]) = stg[it];
    __syncthreads();

    const float* bias = (m == 0) ? bq : (m == 1) ? bk : (m == 2) ? bv
                      : (m == 3) ? bs : bqE;
    f32x4 acc[8];
#pragma unroll
    for (int nf = 0; nf < 8; ++nf) acc[nf] = (f32x4){0.f, 0.f, 0.f, 0.f};
#pragma unroll
    for (int nf = 0; nf < 8; ++nf) {
        const int col = nf * 16 + lrow;
#pragma unroll
        for (int kf = 0; kf < 4; ++kf)
            acc[nf] = __builtin_amdgcn_mfma_f32_16x16x32_bf16(
                af[kf], ldsB(sw, col, kf * 32 + kb), acc[nf], 0, 0, 0);
    }
#pragma unroll
    for (int nf = 0; nf < 8; ++nf) {
        const int col = nf * 16 + lrow;
        const float bb = bias[col];
#pragma unroll
        for (int i = 0; i < 4; ++i) {
            int r = row0 + rq + i;
            if (r < N) {
                float v = acc[nf][i] + bb;
                if (m == 0)      QA[(size_t)r * 256 + col]       = f2bf(v);
                else if (m == 1) KV[(size_t)r * 256 + col]       = f2bf(v);
                else if (m == 2) KV[(size_t)r * 256 + 128 + col] = f2bf(v);
                else if (m == 3) S[(size_t)r * D + col]          = v;
                else             QA[(size_t)r * 256 + 128 + col] = f2bf(v);
            }
        }
    }
}

// ---------------------------------------------------------------------------
// CSR construction: hist -> hierarchical scan -> scatter (srcs + bf16 EA perm)
// ---------------------------------------------------------------------------
__global__ __launch_bounds__(256) void hist_kernel(
    const int* __restrict__ EI, int* __restrict__ deg, int E)
{
    int e = blockIdx.x * 256 + threadIdx.x;
    if (e < E) atomicAdd(&deg[EI[E + e]], 1);
}

__global__ __launch_bounds__(1024) void scanA(
    const int* __restrict__ deg, int* __restrict__ rowptr,
    int* __restrict__ psums, int N)
{
    __shared__ int tmp[1024];
    const int t = threadIdx.x;
    const int i = blockIdx.x * 1024 + t;
    int v = (i < N) ? deg[i] : 0;
    tmp[t] = v;
    __syncthreads();
    for (int off = 1; off < 1024; off <<= 1) {
        int add = (t >= off) ? tmp[t - off] : 0;
        __syncthreads();
        tmp[t] += add;
        __syncthreads();
    }
    if (i < N) rowptr[i + 1] = tmp[t];
    if (t == 1023) psums[blockIdx.x] = tmp[1023];
}

__global__ __launch_bounds__(1024) void scanB(int* __restrict__ psums, int nb)
{
    __shared__ int tmp[1024];
    const int t = threadIdx.x;
    int v = (t < nb) ? psums[t] : 0;
    tmp[t] = v;
    __syncthreads();
    for (int off = 1; off < 1024; off <<= 1) {
        int add = (t >= off) ? tmp[t - off] : 0;
        __syncthreads();
        tmp[t] += add;
        __syncthreads();
    }
    if (t < nb) psums[t] = tmp[t] - v;   // exclusive
}

__global__ __launch_bounds__(256) void scanC(
    int* __restrict__ rowptr, int* __restrict__ cursor,
    const int* __restrict__ psums, int N)
{
    int i = blockIdx.x * 256 + threadIdx.x;
    if (i == 0) { rowptr[0] = 0; cursor[0] = 0; }
    if (i < N) {
        int val = rowptr[i + 1] + psums[i >> 10];
        rowptr[i + 1] = val;
        if (i + 1 < N) cursor[i + 1] = val;
    }
}

__global__ __launch_bounds__(256) void scatter_kernel(
    const int* __restrict__ EI, const float* __restrict__ EA,
    int* __restrict__ cursor, int* __restrict__ srcs,
    unsigned short* __restrict__ EAP, int E)
{
    int e = blockIdx.x * 256 + threadIdx.x;
    if (e >= E) return;
    int dst = EI[E + e];
    int pos = atomicAdd(&cursor[dst], 1);
    srcs[pos] = EI[e];
    const float4* s4 = (const float4*)(EA + (size_t)e * EDIM);
    unsigned short* op = EAP + (size_t)pos * EDIM;
#pragma unroll
    for (int j = 0; j < 4; ++j) {
        float4 a = s4[2 * j], b = s4[2 * j + 1];
        ushort8 u;
        u[0] = f2bf(a.x); u[1] = f2bf(a.y); u[2] = f2bf(a.z); u[3] = f2bf(a.w);
        u[4] = f2bf(b.x); u[5] = f2bf(b.y); u[6] = f2bf(b.z); u[7] = f2bf(b.w);
        *(ushort8*)(op + j * 8) = u;
    }
}

// ---------------------------------------------------------------------------
// gather: 1 wave per node; 4 edge groups x 16 lanes (lane owns 8 dims),
// 2 edges per group per iteration (8 edges in flight / wave).
// Writes (in place into SB): preout = sum(ex*v)/den + skip
// and SAS (bf16) = sum(ex*ea)/den  -> corr GEMM later.
// ---------------------------------------------------------------------------
__global__ __launch_bounds__(256) void gather_pass(
    const int* __restrict__ rowptr, const int* __restrict__ srcs,
    const unsigned short* __restrict__ EAP,
    const unsigned short* __restrict__ QA, const unsigned short* __restrict__ KV,
    float* __restrict__ SB, unsigned short* __restrict__ SAS, int N)
{
    const int lane = threadIdx.x & 63;
    const int wid = threadIdx.x >> 6;
    const int n = blockIdx.x * 4 + wid;
    if (n >= N) return;
    const int g = lane & 15;        // dim slice: d = g*8..+8 (head g>>2)
    const int grp = lane >> 4;      // edge group 0..3
    const int eoff = (g & 3) * 8;   // this lane's EA slice

    float q8[8], qe8[8];
    {
        const unsigned short* qa = QA + (size_t)n * 256 + g * 8;
        bf16x8 qb  = *(const bf16x8*)(qa);
        bf16x8 qeb = *(const bf16x8*)(qa + 128);
#pragma unroll
        for (int j = 0; j < 8; ++j) {
            q8[j]  = bf2f((unsigned short)qb[j]);
            qe8[j] = bf2f((unsigned short)qeb[j]);
        }
    }

    float acc[8], sa[8], den = 0.f;
#pragma unroll
    for (int j = 0; j < 8; ++j) { acc[j] = 0.f; sa[j] = 0.f; }

    const int i0 = rowptr[n], i1 = rowptr[n + 1];

    int iA = i0 + grp, iB = iA + 4;
    int sA = (iA < i1) ? srcs[iA] : -1;
    int sB = (iB < i1) ? srcs[iB] : -1;

    for (int b = i0; b < i1; b += 8) {
        // prefetch next iteration's srcs (full iteration of cover)
        const int iA2 = iA + 8, iB2 = iB + 8;
        const int sA2 = (iA2 < i1) ? srcs[iA2] : -1;
        const int sB2 = (iB2 < i1) ? srcs[iB2] : -1;

        // issue all 6 data loads up front
        bf16x8 kA = {0,0,0,0,0,0,0,0}, vA = kA, eA = kA;
        bf16x8 kB = kA, vB = kA, eB = kA;
        if (sA >= 0) {
            const unsigned short* kv = KV + (size_t)sA * 256 + g * 8;
            kA = *(const bf16x8*)(kv);
            vA = *(const bf16x8*)(kv + 128);
            eA = *(const bf16x8*)(EAP + (size_t)iA * EDIM + eoff);
        }
        if (sB >= 0) {
            const unsigned short* kv = KV + (size_t)sB * 256 + g * 8;
            kB = *(const bf16x8*)(kv);
            vB = *(const bf16x8*)(kv + 128);
            eB = *(const bf16x8*)(EAP + (size_t)iB * EDIM + eoff);
        }

        // edge A
        {
            float ef[8];
            float p = 0.f;
#pragma unroll
            for (int j = 0; j < 8; ++j) {
                ef[j] = bf2f((unsigned short)eA[j]);
                p = fmaf(q8[j], bf2f((unsigned short)kA[j]),
                         fmaf(ef[j], qe8[j], p));
            }
            p = quad_add(p);
            const float ex = (sA >= 0) ? __expf(p * 0.17677669529663689f) : 0.f;
            den += ex;
#pragma unroll
            for (int j = 0; j < 8; ++j) {
                acc[j] = fmaf(ex, bf2f((unsigned short)vA[j]), acc[j]);
                sa[j]  = fmaf(ex, ef[j], sa[j]);
            }
        }
        // edge B
        {
            float ef[8];
            float p = 0.f;
#pragma unroll
            for (int j = 0; j < 8; ++j) {
                ef[j] = bf2f((unsigned short)eB[j]);
                p = fmaf(q8[j], bf2f((unsigned short)kB[j]),
                         fmaf(ef[j], qe8[j], p));
            }
            p = quad_add(p);
            const float ex = (sB >= 0) ? __expf(p * 0.17677669529663689f) : 0.f;
            den += ex;
#pragma unroll
            for (int j = 0; j < 8; ++j) {
                acc[j] = fmaf(ex, bf2f((unsigned short)vB[j]), acc[j]);
                sa[j]  = fmaf(ex, ef[j], sa[j]);
            }
        }
        iA = iA2; iB = iB2; sA = sA2; sB = sB2;
    }

    // combine the 4 edge groups (once per node)
#pragma unroll
    for (int off = 16; off <= 32; off <<= 1) {
        den += __shfl_xor(den, off, 64);
#pragma unroll
        for (int j = 0; j < 8; ++j) {
            acc[j] += __shfl_xor(acc[j], off, 64);
            sa[j]  += __shfl_xor(sa[j],  off, 64);
        }
    }

    if (grp == 0) {
        const float rden = 1.f / (den + 1e-16f);
        float* so = SB + (size_t)n * D + g * 8;
        unsigned short* po = SAS + (size_t)n * D + g * 8;
#pragma unroll
        for (int j = 0; j < 8; ++j) {
            so[j] = fmaf(acc[j], rden, so[j]);    // + skip (in place)
            po[j] = f2bf(sa[j] * rden);
        }
    }
}

// ---------------------------------------------------------------------------
// combine_mlp1: OUT = preout + SAS @ WtCorr (C-init = preout from SB);
// H1 = gelu(OUT @ W1 + b1). Weights staged sequentially in one 32KB LDS
// buffer; OUT bounced through bf16 LDS (pad 136). OUT persists into SB.
// ---------------------------------------------------------------------------
__global__ __launch_bounds__(256) void combine_mlp1(
    float* __restrict__ SB, const unsigned short* __restrict__ SAS,
    const unsigned short* __restrict__ WtC, const unsigned short* __restrict__ Wt1,
    const float* __restrict__ b1, unsigned short* __restrict__ H1, int N)
{
    __shared__ unsigned short sw[16384];
    __shared__ unsigned short bounce[64 * 136];
    const int t = threadIdx.x;
    const int lane = t & 63;
    const int w = t >> 6;
    const int row0 = blockIdx.x * 64 + w * 16;
    const int lrow = lane & 15;
    const int kb = (lane >> 4) * 8;
    const int rq = (lane >> 4) * 4;

    // stage WtC (loads first; A-frags + C-init overlap the latency)
    ushort8 stg[8];
#pragma unroll
    for (int it = 0; it < 8; ++it)
        stg[it] = *(const ushort8*)(WtC + (t + it * 256) * 8);

    bf16x8 af[4];
    {
        int ar = row0 + lrow; if (ar > N - 1) ar = N - 1;
        const unsigned short* xr = SAS + (size_t)ar * D + kb;
#pragma unroll
        for (int kf = 0; kf < 4; ++kf) af[kf] = *(const bf16x8*)(xr + kf * 32);
    }
    f32x4 acc[8];
#pragma unroll
    for (int nf = 0; nf < 8; ++nf) {
        const int col = nf * 16 + lrow;
#pragma unroll
        for (int i = 0; i < 4; ++i) {
            int r = row0 + rq + i;
            acc[nf][i] = (r < N) ? SB[(size_t)r * D + col] : 0.f;
        }
    }

#pragma unroll
    for (int it = 0; it < 8; ++it)
        *(ushort8*)(&sw[(t + it * 256) * 8]) = stg[it];
    __syncthreads();

    // GEMM1: OUT = preout + SAS @ WtCorr
#pragma unroll
    for (int nf = 0; nf < 8; ++nf) {
        const int col = nf * 16 + lrow;
#pragma unroll
        for (int kf = 0; kf < 4; ++kf)
            acc[nf] = __builtin_amdgcn_mfma_f32_16x16x32_bf16(
                af[kf], ldsB(sw, col, kf * 32 + kb), acc[nf], 0, 0, 0);
    }
    __syncthreads();   // all GEMM1 LDS reads done before re-stage

    // stage Wt1 + write OUT (global + bf16 bounce)
#pragma unroll
    for (int it = 0; it < 8; ++it)
        stg[it] = *(const ushort8*)(Wt1 + (t + it * 256) * 8);
#pragma unroll
    for (int nf = 0; nf < 8; ++nf) {
        const int col = nf * 16 + lrow;
#pragma unroll
        for (int i = 0; i < 4; ++i) {
            int r = row0 + rq + i;
            float v = acc[nf][i];
            bounce[(w * 16 + rq + i) * 136 + col] = f2bf(v);
            if (r < N) SB[(size_t)r * D + col] = v;   // OUT
        }
    }
#pragma unroll
    for (int it = 0; it < 8; ++it)
        *(ushort8*)(&sw[(t + it * 256) * 8]) = stg[it];
    __syncthreads();

    // GEMM2: H1 = gelu(OUT @ W1 + b1)
    bf16x8 af2[4];
#pragma unroll
    for (int kf = 0; kf < 4; ++kf)
        af2[kf] = *(const bf16x8*)(&bounce[(w * 16 + lrow) * 136 + kb + kf * 32]);
    f32x4 acc2[8];
#pragma unroll
    for (int nf = 0; nf < 8; ++nf) acc2[nf] = (f32x4){0.f, 0.f, 0.f, 0.f};
#pragma unroll
    for (int nf = 0; nf < 8; ++nf) {
        const int col = nf * 16 + lrow;
#pragma unroll
        for (int kf = 0; kf < 4; ++kf)
            acc2[nf] = __builtin_amdgcn_mfma_f32_16x16x32_bf16(
                af2[kf], ldsB(sw, col, kf * 32 + kb), acc2[nf], 0, 0, 0);
    }
#pragma unroll
    for (int nf = 0; nf < 8; ++nf) {
        const int col = nf * 16 + lrow;
        const float bb = b1[col];
#pragma unroll
        for (int i = 0; i < 4; ++i) {
            int r = row0 + rq + i;
            if (r < N) H1[(size_t)r * D + col] = f2bf(gelu_fast(acc2[nf][i] + bb));
        }
    }
}

// ---------------------------------------------------------------------------
// mlp2: FINAL = OUT + gelu(H1 @ W2 + b2). Wt2 staged to LDS.
// ---------------------------------------------------------------------------
__global__ __launch_bounds__(256) void mlp2_kernel(
    const unsigned short* __restrict__ H1, const float* __restrict__ OUT,
    const unsigned short* __restrict__ Wt2, const float* __restrict__ b2,
    float* __restrict__ FINAL, int N)
{
    __shared__ unsigned short sw[16384];
    const int t = threadIdx.x;
    const int lane = t & 63;
    const int w = t >> 6;
    const int row0 = blockIdx.x * 64 + w * 16;
    const int lrow = lane & 15;
    const int kb = (lane >> 4) * 8;
    const int rq = (lane >> 4) * 4;

    ushort8 stg[8];
#pragma unroll
    for (int it = 0; it < 8; ++it)
        stg[it] = *(const ushort8*)(Wt2 + (t + it * 256) * 8);

    bf16x8 af[4];
    {
        int ar = row0 + lrow; if (ar > N - 1) ar = N - 1;
        const unsigned short* xr = H1 + (size_t)ar * D + kb;
#pragma unroll
        for (int kf = 0; kf < 4; ++kf) af[kf] = *(const bf16x8*)(xr + kf * 32);
    }

#pragma unroll
    for (int it = 0; it < 8; ++it)
        *(ushort8*)(&sw[(t + it * 256) * 8]) = stg[it];
    __syncthreads();

    f32x4 acc[8];
#pragma unroll
    for (int nf = 0; nf < 8; ++nf) acc[nf] = (f32x4){0.f, 0.f, 0.f, 0.f};
#pragma unroll
    for (int nf = 0; nf < 8; ++nf) {
        const int col = nf * 16 + lrow;
#pragma unroll
        for (int kf = 0; kf < 4; ++kf)
            acc[nf] = __builtin_amdgcn_mfma_f32_16x16x32_bf16(
                af[kf], ldsB(sw, col, kf * 32 + kb), acc[nf], 0, 0, 0);
    }
#pragma unroll
    for (int nf = 0; nf < 8; ++nf) {
        const int col = nf * 16 + lrow;
        const float bb = b2[col];
#pragma unroll
        for (int i = 0; i < 4; ++i) {
            int r = row0 + rq + i;
            if (r < N) {
                size_t o = (size_t)r * D + col;
                FINAL[o] = OUT[o] + gelu_fast(acc[nf][i] + bb);
            }
        }
    }
}

// ---------------------------------------------------------------------------
extern "C" void kernel_launch(void* const* d_in, const int* in_sizes, int n_in,
                              void* d_out, int out_size, void* d_ws, size_t ws_size,
                              hipStream_t stream)
{
    const float* x   = (const float*)d_in[0];
    const int*   EI  = (const int*)  d_in[1];
    const float* EA  = (const float*)d_in[2];
    const float* Wq  = (const float*)d_in[3];
    const float* bq  = (const float*)d_in[4];
    const float* Wk  = (const float*)d_in[5];
    const float* bk  = (const float*)d_in[6];
    const float* Wv  = (const float*)d_in[7];
    const float* bv  = (const float*)d_in[8];
    const float* We  = (const float*)d_in[9];
    const float* Wsk = (const float*)d_in[10];
    const float* bsk = (const float*)d_in[11];
    const float* W1  = (const float*)d_in[12];
    const float* b1  = (const float*)d_in[13];
    const float* W2  = (const float*)d_in[14];
    const float* b2  = (const float*)d_in[15];

    const int N = in_sizes[0] / D;
    const int E = in_sizes[1] / 2;

    char* p = (char*)d_ws;
    auto alloc = [&](size_t bytes) -> void* {
        void* r = (void*)p;
        p += (bytes + 255) & ~(size_t)255;
        return r;
    };
    float*          Sb     = (float*)         alloc((size_t)N * D * 4); // skip->preout->OUT
    unsigned short* QAb    = (unsigned short*)alloc((size_t)N * 256 * 2); // [Q|QE]; later H1
    unsigned short* KVb    = (unsigned short*)alloc((size_t)N * 256 * 2); // [K|V]
    unsigned short* SASb   = (unsigned short*)alloc((size_t)N * D * 2);
    unsigned short* EAPb   = (unsigned short*)alloc((size_t)E * EDIM * 2);
    int*            srcsb  = (int*)           alloc((size_t)E * 4);
    unsigned short* Wt     = (unsigned short*)alloc((size_t)8 * 16384 * 2);
    float*          bqEb   = (float*)         alloc((size_t)128 * 4);
    int*            deg    = (int*)           alloc((size_t)N * 4);
    int*            rowptr = (int*)           alloc((size_t)(N + 1) * 4);
    int*            cursor = (int*)           alloc((size_t)(N + 1) * 4);
    int*            psums  = (int*)           alloc((size_t)1024 * 4);

    unsigned short* H1b = QAb;   // alias: QA dead after gather_pass

    hipMemsetAsync(deg, 0, (size_t)N * sizeof(int), stream);

    const int NB = (N + 63) / 64;
    const int EB = (E + 255) / 256;
    const int SB_ = (N + 1023) / 1024;

    prep_wt<<<513, 256, 0, stream>>>(Wq, Wk, Wv, Wsk, W1, W2, We, bq, Wt, bqEb);

    gemm_qkvs<<<dim3(NB, 5), 256, 0, stream>>>(x, Wt, bq, bk, bv, bsk, bqEb,
                                               QAb, KVb, Sb, N);

    hist_kernel<<<EB, 256, 0, stream>>>(EI, deg, E);
    scanA<<<SB_, 1024, 0, stream>>>(deg, rowptr, psums, N);
    scanB<<<1, 1024, 0, stream>>>(psums, SB_);
    scanC<<<(N + 255) / 256, 256, 0, stream>>>(rowptr, cursor, psums, N);
    scatter_kernel<<<EB, 256, 0, stream>>>(EI, EA, cursor, srcsb, EAPb, E);

    gather_pass<<<(N + 3) / 4, 256, 0, stream>>>(
        rowptr, srcsb, EAPb, QAb, KVb, Sb, SASb, N);

    combine_mlp1<<<NB, 256, 0, stream>>>(Sb, SASb, Wt + (size_t)7 * 16384,
                                         Wt + (size_t)4 * 16384, b1, H1b, N);
    mlp2_kernel<<<NB, 256, 0, stream>>>(H1b, Sb, Wt + (size_t)5 * 16384, b2,
                                        (float*)d_out, N);
}

// Round 8
// 270.274 us; speedup vs baseline: 3.7350x; 1.1070x over previous
//
#include <hip/hip_runtime.h>
#include <math.h>

// ---------------------------------------------------------------------------
// GraphTransformerBlock: TransformerConv (4 heads x 32) + residual MLP.
// Round 8: pipeline compaction.
//  - combine_mlp1 + mlp2 fused into ONE kernel (3 sequential weight stages,
//    OUT/H1 never touch global memory).
//  - scatter and gemm_qkvs fused into ONE launch (independent block ranges
//    overlap on the chip).
//  - hist folded into prep_wt.
// gather_pass unchanged from round 7.
// ---------------------------------------------------------------------------

#define D 128
#define EDIM 32

using bf16x8 = __attribute__((ext_vector_type(8))) short;
using f32x4  = __attribute__((ext_vector_type(4))) float;
using ushort8 = __attribute__((ext_vector_type(8))) unsigned short;

__device__ inline unsigned short f2bf(float f) {
    unsigned int u = __float_as_uint(f);
    u += 0x7FFFu + ((u >> 16) & 1u);          // round-to-nearest-even
    return (unsigned short)(u >> 16);
}
__device__ inline float bf2f(unsigned short h) {
    return __uint_as_float(((unsigned int)h) << 16);
}
__device__ inline float gelu_fast(float x) {
    float x3 = x * x * x;
    float u = 0.7978845608028654f * (x + 0.044715f * x3);
    float t = 1.f - 2.f / (__expf(2.f * u) + 1.f);   // tanh(u)
    return 0.5f * x * (1.f + t);
}
// sum over aligned 4-lane quad via DPP quad_perm (all 4 lanes get the sum)
__device__ inline float quad_add(float x) {
    int a = __builtin_amdgcn_update_dpp(0, __float_as_int(x), 0xB1, 0xF, 0xF, true);
    x += __int_as_float(a);
    a = __builtin_amdgcn_update_dpp(0, __float_as_int(x), 0x4E, 0xF, 0xF, true);
    x += __int_as_float(a);
    return x;
}

// swizzled B-frag read: element (col, kk0..kk0+7) of the staged weight tile
__device__ inline bf16x8 ldsB(const unsigned short* sw, int col, int kk0) {
    return *(const bf16x8*)(sw + col * 128 + (kk0 ^ ((col & 7) << 3)));
}

// ---------------------------------------------------------------------------
// prep_wt_hist: blocks 0..511 build the 8 pre-swizzled bf16 weight tables
//   Wt[m][col*128 + (kk ^ ((col&7)<<3))] = W_m[kk][col]
//   m: 0=Wq 1=Wk 2=Wv 3=Wskip 4=W1 5=W2 6=WqE (inline dot) 7=WtCorr
// block 512: bqE.  blocks 513..: hist (deg atomics) — independent work.
// ---------------------------------------------------------------------------
__global__ __launch_bounds__(256) void prep_wt_hist(
    const float* __restrict__ Wq, const float* __restrict__ Wk,
    const float* __restrict__ Wv, const float* __restrict__ Wsk,
    const float* __restrict__ W1, const float* __restrict__ W2,
    const float* __restrict__ We, const float* __restrict__ bq,
    unsigned short* __restrict__ Wt, float* __restrict__ bqE,
    const int* __restrict__ EI, int* __restrict__ deg, int E)
{
    if (blockIdx.x >= 513) {              // hist tail
        int e = (blockIdx.x - 513) * 256 + threadIdx.x;
        if (e < E) atomicAdd(&deg[EI[E + e]], 1);
        return;
    }
    int t = blockIdx.x * 256 + threadIdx.x;
    int m = t >> 14;
    int r = t & 16383;
    if (m >= 8) {                         // bqE block
        if (r < 128) {
            const int hb = r & 96, k = r & 31;
            const float* wek = We + (size_t)k * D + hb;
            float s = 0.f;
#pragma unroll 8
            for (int c = 0; c < 32; ++c) s = fmaf(bq[hb + c], wek[c], s);
            bqE[r] = s;
        }
        return;
    }
    int col = r & 127, kk = r >> 7;
    float v;
    if (m < 6) {
        const float* W = (m == 0) ? Wq : (m == 1) ? Wk : (m == 2) ? Wv
                       : (m == 3) ? Wsk : (m == 4) ? W1 : W2;
        v = W[(size_t)kk * D + col];
    } else if (m == 6) {
        const int hb = col & 96;
        const float* wqr = Wq + (size_t)kk * D + hb;
        const float* wer = We + (size_t)(col & 31) * D + hb;
        float s = 0.f;
#pragma unroll 8
        for (int c = 0; c < 32; ++c) s = fmaf(wqr[c], wer[c], s);
        v = s;
    } else {
        v = ((kk >> 5) == (col >> 5)) ? We[(size_t)(kk & 31) * D + col] : 0.f;
    }
    Wt[(size_t)m * 16384 + (size_t)col * 128 + (kk ^ ((col & 7) << 3))] = f2bf(v);
}

// ---------------------------------------------------------------------------
// hierarchical scan
// ---------------------------------------------------------------------------
__global__ __launch_bounds__(1024) void scanA(
    const int* __restrict__ deg, int* __restrict__ rowptr,
    int* __restrict__ psums, int N)
{
    __shared__ int tmp[1024];
    const int t = threadIdx.x;
    const int i = blockIdx.x * 1024 + t;
    int v = (i < N) ? deg[i] : 0;
    tmp[t] = v;
    __syncthreads();
    for (int off = 1; off < 1024; off <<= 1) {
        int add = (t >= off) ? tmp[t - off] : 0;
        __syncthreads();
        tmp[t] += add;
        __syncthreads();
    }
    if (i < N) rowptr[i + 1] = tmp[t];
    if (t == 1023) psums[blockIdx.x] = tmp[1023];
}

__global__ __launch_bounds__(1024) void scanB(int* __restrict__ psums, int nb)
{
    __shared__ int tmp[1024];
    const int t = threadIdx.x;
    int v = (t < nb) ? psums[t] : 0;
    tmp[t] = v;
    __syncthreads();
    for (int off = 1; off < 1024; off <<= 1) {
        int add = (t >= off) ? tmp[t - off] : 0;
        __syncthreads();
        tmp[t] += add;
        __syncthreads();
    }
    if (t < nb) psums[t] = tmp[t] - v;   // exclusive
}

__global__ __launch_bounds__(256) void scanC(
    int* __restrict__ rowptr, int* __restrict__ cursor,
    const int* __restrict__ psums, int N)
{
    int i = blockIdx.x * 256 + threadIdx.x;
    if (i == 0) { rowptr[0] = 0; cursor[0] = 0; }
    if (i < N) {
        int val = rowptr[i + 1] + psums[i >> 10];
        rowptr[i + 1] = val;
        if (i + 1 < N) cursor[i + 1] = val;
    }
}

// ---------------------------------------------------------------------------
// mega: blocks [0,EB) = scatter (CSR perm of srcs + bf16 edge_attr);
//       blocks [EB, EB+5*NB) = gemm slices m=0..4 (Q,K,V,skip,QE).
// The two halves are independent and overlap across CUs.
// ---------------------------------------------------------------------------
__global__ __launch_bounds__(256) void mega_scatter_gemm(
    const int* __restrict__ EI, const float* __restrict__ EA,
    int* __restrict__ cursor, int* __restrict__ srcs,
    unsigned short* __restrict__ EAP, int E, int EB,
    const float* __restrict__ x, const unsigned short* __restrict__ Wt,
    const float* __restrict__ bq, const float* __restrict__ bk,
    const float* __restrict__ bv, const float* __restrict__ bs,
    const float* __restrict__ bqE,
    unsigned short* __restrict__ QA, unsigned short* __restrict__ KV,
    float* __restrict__ S, int N, int NB)
{
    __shared__ unsigned short sw[16384];
    const int t = threadIdx.x;

    if ((int)blockIdx.x < EB) {
        // ------- scatter -------
        int e = blockIdx.x * 256 + t;
        if (e >= E) return;
        int dst = EI[E + e];
        int pos = atomicAdd(&cursor[dst], 1);
        srcs[pos] = EI[e];
        const float4* s4 = (const float4*)(EA + (size_t)e * EDIM);
        unsigned short* op = EAP + (size_t)pos * EDIM;
#pragma unroll
        for (int j = 0; j < 4; ++j) {
            float4 a = s4[2 * j], b = s4[2 * j + 1];
            ushort8 u;
            u[0] = f2bf(a.x); u[1] = f2bf(a.y); u[2] = f2bf(a.z); u[3] = f2bf(a.w);
            u[4] = f2bf(b.x); u[5] = f2bf(b.y); u[6] = f2bf(b.z); u[7] = f2bf(b.w);
            *(ushort8*)(op + j * 8) = u;
        }
        return;
    }

    // ------- gemm slice -------
    const int bid = blockIdx.x - EB;
    const int m = bid / NB;
    const int bx = bid - m * NB;
    const int widx = (m < 4) ? m : 6;
    const int lane = t & 63;
    const int w = t >> 6;
    const int row0 = bx * 64 + w * 16;
    const int lrow = lane & 15;
    const int kb = (lane >> 4) * 8;
    const int rq = (lane >> 4) * 4;

    const unsigned short* gsrc = Wt + (size_t)widx * 16384;
    ushort8 stg[8];
#pragma unroll
    for (int it = 0; it < 8; ++it)
        stg[it] = *(const ushort8*)(gsrc + (t + it * 256) * 8);

    bf16x8 af[4];
    {
        int ar = row0 + lrow; if (ar > N - 1) ar = N - 1;
        const float* xr = x + (size_t)ar * D + kb;
#pragma unroll
        for (int kf = 0; kf < 4; ++kf) {
            float4 p0 = *(const float4*)(xr + kf * 32);
            float4 p1 = *(const float4*)(xr + kf * 32 + 4);
            bf16x8 a;
            a[0] = (short)f2bf(p0.x); a[1] = (short)f2bf(p0.y);
            a[2] = (short)f2bf(p0.z); a[3] = (short)f2bf(p0.w);
            a[4] = (short)f2bf(p1.x); a[5] = (short)f2bf(p1.y);
            a[6] = (short)f2bf(p1.z); a[7] = (short)f2bf(p1.w);
            af[kf] = a;
        }
    }

#pragma unroll
    for (int it = 0; it < 8; ++it)
        *(ushort8*)(&sw[(t + it * 256) * 8]) = stg[it];
    __syncthreads();

    const float* bias = (m == 0) ? bq : (m == 1) ? bk : (m == 2) ? bv
                      : (m == 3) ? bs : bqE;
    f32x4 acc[8];
#pragma unroll
    for (int nf = 0; nf < 8; ++nf) acc[nf] = (f32x4){0.f, 0.f, 0.f, 0.f};
#pragma unroll
    for (int nf = 0; nf < 8; ++nf) {
        const int col = nf * 16 + lrow;
#pragma unroll
        for (int kf = 0; kf < 4; ++kf)
            acc[nf] = __builtin_amdgcn_mfma_f32_16x16x32_bf16(
                af[kf], ldsB(sw, col, kf * 32 + kb), acc[nf], 0, 0, 0);
    }
#pragma unroll
    for (int nf = 0; nf < 8; ++nf) {
        const int col = nf * 16 + lrow;
        const float bb = bias[col];
#pragma unroll
        for (int i = 0; i < 4; ++i) {
            int r = row0 + rq + i;
            if (r < N) {
                float v = acc[nf][i] + bb;
                if (m == 0)      QA[(size_t)r * 256 + col]       = f2bf(v);
                else if (m == 1) KV[(size_t)r * 256 + col]       = f2bf(v);
                else if (m == 2) KV[(size_t)r * 256 + 128 + col] = f2bf(v);
                else if (m == 3) S[(size_t)r * D + col]          = v;
                else             QA[(size_t)r * 256 + 128 + col] = f2bf(v);
            }
        }
    }
}

// ---------------------------------------------------------------------------
// gather: 1 wave per node; 4 edge groups x 16 lanes (lane owns 8 dims),
// 2 edges per group per iteration (8 edges in flight / wave).
// ---------------------------------------------------------------------------
__global__ __launch_bounds__(256) void gather_pass(
    const int* __restrict__ rowptr, const int* __restrict__ srcs,
    const unsigned short* __restrict__ EAP,
    const unsigned short* __restrict__ QA, const unsigned short* __restrict__ KV,
    float* __restrict__ SB, unsigned short* __restrict__ SAS, int N)
{
    const int lane = threadIdx.x & 63;
    const int wid = threadIdx.x >> 6;
    const int n = blockIdx.x * 4 + wid;
    if (n >= N) return;
    const int g = lane & 15;        // dim slice: d = g*8..+8 (head g>>2)
    const int grp = lane >> 4;      // edge group 0..3
    const int eoff = (g & 3) * 8;   // this lane's EA slice

    float q8[8], qe8[8];
    {
        const unsigned short* qa = QA + (size_t)n * 256 + g * 8;
        bf16x8 qb  = *(const bf16x8*)(qa);
        bf16x8 qeb = *(const bf16x8*)(qa + 128);
#pragma unroll
        for (int j = 0; j < 8; ++j) {
            q8[j]  = bf2f((unsigned short)qb[j]);
            qe8[j] = bf2f((unsigned short)qeb[j]);
        }
    }

    float acc[8], sa[8], den = 0.f;
#pragma unroll
    for (int j = 0; j < 8; ++j) { acc[j] = 0.f; sa[j] = 0.f; }

    const int i0 = rowptr[n], i1 = rowptr[n + 1];

    int iA = i0 + grp, iB = iA + 4;
    int sA = (iA < i1) ? srcs[iA] : -1;
    int sB = (iB < i1) ? srcs[iB] : -1;

    for (int b = i0; b < i1; b += 8) {
        const int iA2 = iA + 8, iB2 = iB + 8;
        const int sA2 = (iA2 < i1) ? srcs[iA2] : -1;
        const int sB2 = (iB2 < i1) ? srcs[iB2] : -1;

        bf16x8 kA = {0,0,0,0,0,0,0,0}, vA = kA, eA = kA;
        bf16x8 kB = kA, vB = kA, eB = kA;
        if (sA >= 0) {
            const unsigned short* kv = KV + (size_t)sA * 256 + g * 8;
            kA = *(const bf16x8*)(kv);
            vA = *(const bf16x8*)(kv + 128);
            eA = *(const bf16x8*)(EAP + (size_t)iA * EDIM + eoff);
        }
        if (sB >= 0) {
            const unsigned short* kv = KV + (size_t)sB * 256 + g * 8;
            kB = *(const bf16x8*)(kv);
            vB = *(const bf16x8*)(kv + 128);
            eB = *(const bf16x8*)(EAP + (size_t)iB * EDIM + eoff);
        }

        {
            float ef[8];
            float p = 0.f;
#pragma unroll
            for (int j = 0; j < 8; ++j) {
                ef[j] = bf2f((unsigned short)eA[j]);
                p = fmaf(q8[j], bf2f((unsigned short)kA[j]),
                         fmaf(ef[j], qe8[j], p));
            }
            p = quad_add(p);
            const float ex = (sA >= 0) ? __expf(p * 0.17677669529663689f) : 0.f;
            den += ex;
#pragma unroll
            for (int j = 0; j < 8; ++j) {
                acc[j] = fmaf(ex, bf2f((unsigned short)vA[j]), acc[j]);
                sa[j]  = fmaf(ex, ef[j], sa[j]);
            }
        }
        {
            float ef[8];
            float p = 0.f;
#pragma unroll
            for (int j = 0; j < 8; ++j) {
                ef[j] = bf2f((unsigned short)eB[j]);
                p = fmaf(q8[j], bf2f((unsigned short)kB[j]),
                         fmaf(ef[j], qe8[j], p));
            }
            p = quad_add(p);
            const float ex = (sB >= 0) ? __expf(p * 0.17677669529663689f) : 0.f;
            den += ex;
#pragma unroll
            for (int j = 0; j < 8; ++j) {
                acc[j] = fmaf(ex, bf2f((unsigned short)vB[j]), acc[j]);
                sa[j]  = fmaf(ex, ef[j], sa[j]);
            }
        }
        iA = iA2; iB = iB2; sA = sA2; sB = sB2;
    }

#pragma unroll
    for (int off = 16; off <= 32; off <<= 1) {
        den += __shfl_xor(den, off, 64);
#pragma unroll
        for (int j = 0; j < 8; ++j) {
            acc[j] += __shfl_xor(acc[j], off, 64);
            sa[j]  += __shfl_xor(sa[j],  off, 64);
        }
    }

    if (grp == 0) {
        const float rden = 1.f / (den + 1e-16f);
        float* so = SB + (size_t)n * D + g * 8;
        unsigned short* po = SAS + (size_t)n * D + g * 8;
#pragma unroll
        for (int j = 0; j < 8; ++j) {
            so[j] = fmaf(acc[j], rden, so[j]);    // + skip (in place)
            po[j] = f2bf(sa[j] * rden);
        }
    }
}

// ---------------------------------------------------------------------------
// fused_mlp: OUT = preout + SAS @ WtCorr; H1 = gelu(OUT@W1+b1);
//            FINAL = OUT + gelu(H1@W2+b2).
// One kernel, 3 sequential 32KB weight stages; OUT kept in registers,
// OUT/H1 bf16 bounced through LDS for the next GEMM's A-frags.
// ---------------------------------------------------------------------------
__global__ __launch_bounds__(256) void fused_mlp(
    const float* __restrict__ SB, const unsigned short* __restrict__ SAS,
    const unsigned short* __restrict__ WtC, const unsigned short* __restrict__ Wt1,
    const unsigned short* __restrict__ Wt2,
    const float* __restrict__ b1, const float* __restrict__ b2,
    float* __restrict__ FINAL, int N)
{
    __shared__ unsigned short sw[16384];
    __shared__ unsigned short bounce[64 * 136];
    const int t = threadIdx.x;
    const int lane = t & 63;
    const int w = t >> 6;
    const int row0 = blockIdx.x * 64 + w * 16;
    const int lrow = lane & 15;
    const int kb = (lane >> 4) * 8;
    const int rq = (lane >> 4) * 4;

    // ---- stage WtC; A-frags (SAS) + C-init (preout) overlap the latency
    ushort8 stg[8];
#pragma unroll
    for (int it = 0; it < 8; ++it)
        stg[it] = *(const ushort8*)(WtC + (t + it * 256) * 8);

    bf16x8 af[4];
    {
        int ar = row0 + lrow; if (ar > N - 1) ar = N - 1;
        const unsigned short* xr = SAS + (size_t)ar * D + kb;
#pragma unroll
        for (int kf = 0; kf < 4; ++kf) af[kf] = *(const bf16x8*)(xr + kf * 32);
    }
    f32x4 out[8];
#pragma unroll
    for (int nf = 0; nf < 8; ++nf) {
        const int col = nf * 16 + lrow;
#pragma unroll
        for (int i = 0; i < 4; ++i) {
            int r = row0 + rq + i;
            out[nf][i] = (r < N) ? SB[(size_t)r * D + col] : 0.f;
        }
    }
#pragma unroll
    for (int it = 0; it < 8; ++it)
        *(ushort8*)(&sw[(t + it * 256) * 8]) = stg[it];
    __syncthreads();

    // ---- GEMM1: OUT = preout + SAS @ WtCorr
#pragma unroll
    for (int nf = 0; nf < 8; ++nf) {
        const int col = nf * 16 + lrow;
#pragma unroll
        for (int kf = 0; kf < 4; ++kf)
            out[nf] = __builtin_amdgcn_mfma_f32_16x16x32_bf16(
                af[kf], ldsB(sw, col, kf * 32 + kb), out[nf], 0, 0, 0);
    }
    __syncthreads();   // GEMM1 sw reads done

    // ---- bounce OUT (bf16) + stage Wt1
#pragma unroll
    for (int it = 0; it < 8; ++it)
        stg[it] = *(const ushort8*)(Wt1 + (t + it * 256) * 8);
#pragma unroll
    for (int nf = 0; nf < 8; ++nf) {
        const int col = nf * 16 + lrow;
#pragma unroll
        for (int i = 0; i < 4; ++i)
            bounce[(w * 16 + rq + i) * 136 + col] = f2bf(out[nf][i]);
    }
#pragma unroll
    for (int it = 0; it < 8; ++it)
        *(ushort8*)(&sw[(t + it * 256) * 8]) = stg[it];
    __syncthreads();

    // ---- GEMM2: H1 = gelu(OUT @ W1 + b1)
    bf16x8 af2[4];
#pragma unroll
    for (int kf = 0; kf < 4; ++kf)
        af2[kf] = *(const bf16x8*)(&bounce[(w * 16 + lrow) * 136 + kb + kf * 32]);
    f32x4 acc2[8];
#pragma unroll
    for (int nf = 0; nf < 8; ++nf) acc2[nf] = (f32x4){0.f, 0.f, 0.f, 0.f};
#pragma unroll
    for (int nf = 0; nf < 8; ++nf) {
        const int col = nf * 16 + lrow;
#pragma unroll
        for (int kf = 0; kf < 4; ++kf)
            acc2[nf] = __builtin_amdgcn_mfma_f32_16x16x32_bf16(
                af2[kf], ldsB(sw, col, kf * 32 + kb), acc2[nf], 0, 0, 0);
    }
    __syncthreads();   // GEMM2 sw + bounce reads done

    // ---- bounce H1 (bf16) + stage Wt2
#pragma unroll
    for (int it = 0; it < 8; ++it)
        stg[it] = *(const ushort8*)(Wt2 + (t + it * 256) * 8);
#pragma unroll
    for (int nf = 0; nf < 8; ++nf) {
        const int col = nf * 16 + lrow;
        const float bb = b1[col];
#pragma unroll
        for (int i = 0; i < 4; ++i)
            bounce[(w * 16 + rq + i) * 136 + col] = f2bf(gelu_fast(acc2[nf][i] + bb));
    }
#pragma unroll
    for (int it = 0; it < 8; ++it)
        *(ushort8*)(&sw[(t + it * 256) * 8]) = stg[it];
    __syncthreads();

    // ---- GEMM3 + epilogue: FINAL = OUT + gelu(H1 @ W2 + b2)
    bf16x8 af3[4];
#pragma unroll
    for (int kf = 0; kf < 4; ++kf)
        af3[kf] = *(const bf16x8*)(&bounce[(w * 16 + lrow) * 136 + kb + kf * 32]);
    f32x4 acc3[8];
#pragma unroll
    for (int nf = 0; nf < 8; ++nf) acc3[nf] = (f32x4){0.f, 0.f, 0.f, 0.f};
#pragma unroll
    for (int nf = 0; nf < 8; ++nf) {
        const int col = nf * 16 + lrow;
#pragma unroll
        for (int kf = 0; kf < 4; ++kf)
            acc3[nf] = __builtin_amdgcn_mfma_f32_16x16x32_bf16(
                af3[kf], ldsB(sw, col, kf * 32 + kb), acc3[nf], 0, 0, 0);
    }
#pragma unroll
    for (int nf = 0; nf < 8; ++nf) {
        const int col = nf * 16 + lrow;
        const float bb = b2[col];
#pragma unroll
        for (int i = 0; i < 4; ++i) {
            int r = row0 + rq + i;
            if (r < N)
                FINAL[(size_t)r * D + col] = out[nf][i] + gelu_fast(acc3[nf][i] + bb);
        }
    }
}

// ---------------------------------------------------------------------------
extern "C" void kernel_launch(void* const* d_in, const int* in_sizes, int n_in,
                              void* d_out, int out_size, void* d_ws, size_t ws_size,
                              hipStream_t stream)
{
    const float* x   = (const float*)d_in[0];
    const int*   EI  = (const int*)  d_in[1];
    const float* EA  = (const float*)d_in[2];
    const float* Wq  = (const float*)d_in[3];
    const float* bq  = (const float*)d_in[4];
    const float* Wk  = (const float*)d_in[5];
    const float* bk  = (const float*)d_in[6];
    const float* Wv  = (const float*)d_in[7];
    const float* bv  = (const float*)d_in[8];
    const float* We  = (const float*)d_in[9];
    const float* Wsk = (const float*)d_in[10];
    const float* bsk = (const float*)d_in[11];
    const float* W1  = (const float*)d_in[12];
    const float* b1  = (const float*)d_in[13];
    const float* W2  = (const float*)d_in[14];
    const float* b2  = (const float*)d_in[15];

    const int N = in_sizes[0] / D;
    const int E = in_sizes[1] / 2;

    char* p = (char*)d_ws;
    auto alloc = [&](size_t bytes) -> void* {
        void* r = (void*)p;
        p += (bytes + 255) & ~(size_t)255;
        return r;
    };
    float*          Sb     = (float*)         alloc((size_t)N * D * 4);   // skip -> preout
    unsigned short* QAb    = (unsigned short*)alloc((size_t)N * 256 * 2); // [Q|QE]
    unsigned short* KVb    = (unsigned short*)alloc((size_t)N * 256 * 2); // [K|V]
    unsigned short* SASb   = (unsigned short*)alloc((size_t)N * D * 2);
    unsigned short* EAPb   = (unsigned short*)alloc((size_t)E * EDIM * 2);
    int*            srcsb  = (int*)           alloc((size_t)E * 4);
    unsigned short* Wt     = (unsigned short*)alloc((size_t)8 * 16384 * 2);
    float*          bqEb   = (float*)         alloc((size_t)128 * 4);
    int*            deg    = (int*)           alloc((size_t)N * 4);
    int*            rowptr = (int*)           alloc((size_t)(N + 1) * 4);
    int*            cursor = (int*)           alloc((size_t)(N + 1) * 4);
    int*            psums  = (int*)           alloc((size_t)1024 * 4);

    hipMemsetAsync(deg, 0, (size_t)N * sizeof(int), stream);

    const int NB = (N + 63) / 64;
    const int EB = (E + 255) / 256;
    const int SB_ = (N + 1023) / 1024;

    prep_wt_hist<<<513 + EB, 256, 0, stream>>>(Wq, Wk, Wv, Wsk, W1, W2, We, bq,
                                               Wt, bqEb, EI, deg, E);

    scanA<<<SB_, 1024, 0, stream>>>(deg, rowptr, psums, N);
    scanB<<<1, 1024, 0, stream>>>(psums, SB_);
    scanC<<<(N + 255) / 256, 256, 0, stream>>>(rowptr, cursor, psums, N);

    mega_scatter_gemm<<<EB + 5 * NB, 256, 0, stream>>>(
        EI, EA, cursor, srcsb, EAPb, E, EB,
        x, Wt, bq, bk, bv, bsk, bqEb, QAb, KVb, Sb, N, NB);

    gather_pass<<<(N + 3) / 4, 256, 0, stream>>>(
        rowptr, srcsb, EAPb, QAb, KVb, Sb, SASb, N);

    fused_mlp<<<NB, 256, 0, stream>>>(Sb, SASb,
                                      Wt + (size_t)7 * 16384,
                                      Wt + (size_t)4 * 16384,
                                      Wt + (size_t)5 * 16384,
                                      b1, b2, (float*)d_out, N);
}